// Round 8
// baseline (2231.422 us; speedup 1.0000x reference)
//
#include <hip/hip_runtime.h>
#include <math.h>

#define NN   10000      // nodes
#define DD   512        // node dim
#define NH   8          // node heads (DK=64)
#define NE   120000     // edges (global)
#define NEL  60000      // local edges
#define NLG  600000     // line-graph edges
#define ED   64         // edge dim (EH=8, EDK=8)
#define NEH  8
#define NL   4          // layers
#define QKVW 1536       // fused q|k|v row width

typedef __attribute__((ext_vector_type(8))) short bf16x8;
typedef __attribute__((ext_vector_type(8))) unsigned short u16x8;
typedef __attribute__((ext_vector_type(4))) float f32x4;

__device__ __forceinline__ unsigned short f2b(float f) {
    union { float f; unsigned u; } c; c.f = f;
    unsigned u = c.u;
    unsigned r = u + 0x7FFFu + ((u >> 16) & 1u);
    return (unsigned short)(r >> 16);
}
__device__ __forceinline__ float b2f(unsigned short b) {
    union { unsigned u; float f; } c; c.u = ((unsigned)b) << 16;
    return c.f;
}

// async global->LDS, 16B per lane; LDS dest is wave-uniform base + lane*16 (HW)
__device__ __forceinline__ void gl16(const unsigned short* g, unsigned short* l) {
    __builtin_amdgcn_global_load_lds(
        (const __attribute__((address_space(1))) unsigned int*)g,
        (__attribute__((address_space(3))) unsigned int*)l, 16, 0, 0);
}

// ---------------- elementwise helpers ----------------
static __global__ __launch_bounds__(256)
void zero_k(float* __restrict__ p, int n) {
    int i = blockIdx.x * 256 + threadIdx.x;
    if (i < n) p[i] = 0.0f;
}

static __global__ __launch_bounds__(256)
void castcopy_k(const float* __restrict__ s, float* __restrict__ d,
                unsigned short* __restrict__ db, int n) {
    int i = blockIdx.x * 256 + threadIdx.x;
    if (i < n) { float v = s[i]; if (d) d[i] = v; db[i] = f2b(v); }
}

static __global__ __launch_bounds__(256)
void init_lg_k(const float* __restrict__ rel, const int* __restrict__ ef,
               unsigned short* __restrict__ lgb) {
    int i = blockIdx.x * 256 + threadIdx.x;
    if (i >= NE * ED) return;
    int e = i >> 6, c = i & 63;
    lgb[i] = f2b(rel[ef[e] * ED + c]);
}

static __global__ __launch_bounds__(256)
void gather64_k(const unsigned short* __restrict__ lgb, const int* __restrict__ idx,
                float* __restrict__ el, unsigned short* __restrict__ elb) {
    int i = blockIdx.x * 256 + threadIdx.x;
    if (i >= NEL * ED) return;
    int r = i >> 6;
    unsigned short b = lgb[(long)idx[r] * ED + (i & 63)];
    el[i] = b2f(b); elb[i] = b;
}

// ---------------- LDS-tiled transpose+cast ----------------
static __global__ __launch_bounds__(256)
void ttrans_k(const float* __restrict__ in, unsigned short* __restrict__ out,
              int K, int N, long lstride, int rowStride, int rowOff, int colOff) {
    __shared__ float sm[32][33];
    const int l = blockIdx.z;
    const int kt = blockIdx.x * 32, nt = blockIdx.y * 32;
    const int tx = threadIdx.x & 31, ty = threadIdx.x >> 5;
    const float* ip = in + (size_t)l * K * N;
    #pragma unroll
    for (int r = 0; r < 4; ++r)
        sm[ty + 8 * r][tx] = ip[(size_t)(kt + ty + 8 * r) * N + nt + tx];
    __syncthreads();
    unsigned short* op = out + (size_t)l * lstride;
    #pragma unroll
    for (int r = 0; r < 4; ++r) {
        int n = nt + ty + 8 * r;
        op[(size_t)(rowOff + n) * rowStride + colOff + kt + tx] = f2b(sm[tx][ty + 8 * r]);
    }
}

static __global__ __launch_bounds__(256)
void build_qkvb_k(const float* __restrict__ bq, float* __restrict__ out) {
    int i = blockIdx.x * 256 + threadIdx.x;
    if (i >= NL * QKVW) return;
    int l = i / QKVW, c = i - l * QKVW;
    out[i] = (c < 512) ? bq[l * 512 + c] : 0.0f;
}

static __global__ __launch_bounds__(256)
void ebias_k(const float* __restrict__ ndb, const float* __restrict__ eqb,
             const float* __restrict__ nsb, float* __restrict__ kvb,
             float* __restrict__ qb2) {
    int i = blockIdx.x * 256 + threadIdx.x;
    if (i < NL * 128) kvb[i] = ndb[(i >> 7) * 64 + (i & 63)];
    if (i < NL * 64)  qb2[i] = eqb[i] + nsb[i];
}

// ---------------- CSR build ----------------
static __global__ __launch_bounds__(256)
void hist_k(const int* __restrict__ dst, int* __restrict__ cnt, int n) {
    int i = blockIdx.x * 256 + threadIdx.x;
    if (i < n) atomicAdd(&cnt[dst[i]], 1);
}

static __global__ __launch_bounds__(256)
void scanA_k(const int* __restrict__ cnt, int* __restrict__ off,
             int* __restrict__ bsum, int n) {
    __shared__ int sm[256];
    const int t = threadIdx.x;
    const int i = blockIdx.x * 256 + t;
    int v = (i < n) ? cnt[i] : 0;
    sm[t] = v; __syncthreads();
    int x = v;
    #pragma unroll
    for (int d = 1; d < 256; d <<= 1) {
        int y = (t >= d) ? sm[t - d] : 0;
        __syncthreads();
        x += y; sm[t] = x; __syncthreads();
    }
    if (i < n) off[i] = x - v;
    if (t == 255) bsum[blockIdx.x] = x;
}

static __global__ __launch_bounds__(1024)
void scanB_k(int* __restrict__ bsum, int nb) {
    __shared__ int sm[1024];
    const int t = threadIdx.x;
    int v = (t < nb) ? bsum[t] : 0;
    sm[t] = v; __syncthreads();
    int x = v;
    #pragma unroll
    for (int d = 1; d < 1024; d <<= 1) {
        int y = (t >= d) ? sm[t - d] : 0;
        __syncthreads();
        x += y; sm[t] = x; __syncthreads();
    }
    if (t < nb) bsum[t] = x - v;
}

static __global__ __launch_bounds__(256)
void scanC_k(const int* __restrict__ bsum, int* __restrict__ off,
             int* __restrict__ cur, int n) {
    int i = blockIdx.x * 256 + threadIdx.x;
    if (i < n) { int o = off[i] + bsum[blockIdx.x]; off[i] = o; cur[i] = o; }
}

static __global__ __launch_bounds__(256)
void scatter_k(const int* __restrict__ dst, int* __restrict__ cur,
               int* __restrict__ ord, int n) {
    int i = blockIdx.x * 256 + threadIdx.x;
    if (i < n) { int p = atomicAdd(&cur[dst[i]], 1); ord[p] = i; }
}

static __global__ __launch_bounds__(256)
void pack_k(const int* __restrict__ gord, const int* __restrict__ gsrc,
            const int* __restrict__ eord, const int* __restrict__ lsrc,
            int2* __restrict__ npack, int* __restrict__ esrc) {
    int i = blockIdx.x * 256 + threadIdx.x;
    if (i < NE) { int e = gord[i]; npack[i] = make_int2(e, gsrc[e]); }
    if (i < NLG) esrc[i] = lsrc[eord[i]];
}

// ---------------- bf16 MFMA GEMM: BK=64, dbuf LDS, global_load_lds ----------
// If A2==null: C = A[M,K] @ Bt[Nc,K]^T; else A-row r = [A[r][0:K1] | A2[idx2[r]][:]]
// LDS content: lds[r][s] = src[r][s ^ (r&7)] (8 slots of 8 bf16 per 64-wide row)
// via pre-swizzled per-lane GLOBAL addr + linear HW dest (rule #21).
template<int BN>
static __global__ __launch_bounds__(256)
void gemm_bf16_k(const unsigned short* __restrict__ A,
                 const unsigned short* __restrict__ A2, const int* __restrict__ idx2,
                 const unsigned short* __restrict__ Bt, const float* __restrict__ bias,
                 const float* __restrict__ addC, float* __restrict__ C,
                 unsigned short* __restrict__ Cb,
                 int M, int K, int Nc, int doRelu, int K1)
{
    constexpr int NI = BN / 32;               // col frags per wave
    constexpr int TSZ = (128 + BN) * 64;      // elems per LDS buffer
    __shared__ unsigned short lds[2 * TSZ];
    const int tid  = threadIdx.x;
    const int lane = tid & 63;
    const int wave = tid >> 6;
    const int wr = (wave >> 1) * 64;
    const int wc = (wave & 1) * (BN / 2);

    // XCD-aware bijective block swizzle (m204)
    const int nwg = gridDim.x * gridDim.y;
    const int hw = blockIdx.y * gridDim.x + blockIdx.x;
    const int q8 = nwg >> 3, r8 = nwg & 7;
    const int xcd = hw & 7, rest = hw >> 3;
    const int logical = (xcd < r8 ? xcd * (q8 + 1) : r8 * (q8 + 1) + (xcd - r8) * q8) + rest;
    const int bm = (logical / gridDim.x) * 128;
    const int bn = (logical % gridDim.x) * BN;

    const int lr = lane >> 3;                 // row within 8-row stripe
    const int colE = ((lane & 7) ^ lr) * 8;   // pre-swizzled source col (elems)

    // stage A tile (128 x 64) for K-offset k0 into buf
    auto stageA = [&](unsigned short* buf, int k0) {
        #pragma unroll
        for (int c = 0; c < 4; ++c) {
            const int rb = wave * 32 + c * 8;
            const int gr = bm + rb + lr;
            const bool ok = gr < M;
            const unsigned short* gsrc;
            if (!A2) {
                gsrc = A + (long)gr * K + k0 + colE;
            } else if (k0 < K1) {
                gsrc = A + (long)gr * K1 + k0 + colE;
            } else {
                int ii = ok ? idx2[gr] : 0;
                gsrc = A2 + (long)ii * DD + (k0 - K1) + colE;
            }
            if (ok) gl16(gsrc, buf + rb * 64);
        }
    };
    // stage B tile (BN x 64)
    auto stageB = [&](unsigned short* buf, int k0) {
        #pragma unroll
        for (int c = 0; c < BN / 32; ++c) {
            const int rb = wave * (BN / 4) + c * 8;
            const int gc = bn + rb + lr;
            if (gc < Nc) gl16(Bt + (long)gc * K + k0 + colE, buf + rb * 64);
        }
    };

    f32x4 acc[4][NI] = {};
    const int rbase = lane & 15;
    const int ks = lane >> 4;

    auto compute = [&](const unsigned short* bA, const unsigned short* bB) {
        #pragma unroll
        for (int sl = 0; sl < 2; ++sl) {
            bf16x8 af[4]; bf16x8 bfr[NI];
            #pragma unroll
            for (int mi = 0; mi < 4; ++mi) {
                int r = wr + mi * 16 + rbase;
                int cc = (sl * 4 + ks) ^ (r & 7);
                af[mi] = *reinterpret_cast<const bf16x8*>(bA + r * 64 + cc * 8);
            }
            #pragma unroll
            for (int ni = 0; ni < NI; ++ni) {
                int r = wc + ni * 16 + rbase;
                int cc = (sl * 4 + ks) ^ (r & 7);
                bfr[ni] = *reinterpret_cast<const bf16x8*>(bB + r * 64 + cc * 8);
            }
            #pragma unroll
            for (int mi = 0; mi < 4; ++mi)
                #pragma unroll
                for (int ni = 0; ni < NI; ++ni)
                    acc[mi][ni] = __builtin_amdgcn_mfma_f32_16x16x32_bf16(
                        af[mi], bfr[ni], acc[mi][ni], 0, 0, 0);
        }
    };

    unsigned short* bufA0 = lds;
    unsigned short* bufB0 = lds + 128 * 64;
    unsigned short* bufA1 = lds + TSZ;
    unsigned short* bufB1 = lds + TSZ + 128 * 64;

    const int nt = K >> 6;
    stageA(bufA0, 0); stageB(bufB0, 0);
    __syncthreads();                          // drains vmcnt: tile 0 landed
    for (int t = 0; t < nt; ++t) {
        unsigned short* cA = (t & 1) ? bufA1 : bufA0;
        unsigned short* cB = (t & 1) ? bufB1 : bufB0;
        unsigned short* nA = (t & 1) ? bufA0 : bufA1;
        unsigned short* nB = (t & 1) ? bufB0 : bufB1;
        if (t + 1 < nt) { stageA(nA, (t + 1) * 64); stageB(nB, (t + 1) * 64); } // issue-early
        compute(cA, cB);                       // hides load latency
        __syncthreads();                       // vmcnt(0)+barrier: next tile ready
    }

    const int colBase = bn + wc + rbase;
    const int rowBase = bm + wr + ks * 4;
    #pragma unroll
    for (int mi = 0; mi < 4; ++mi) {
        #pragma unroll
        for (int j = 0; j < 4; ++j) {
            int r = rowBase + mi * 16 + j;
            if (r >= M) continue;
            long ro = (long)r * Nc;
            #pragma unroll
            for (int ni = 0; ni < NI; ++ni) {
                int cc = colBase + ni * 16;
                if (cc >= Nc) continue;
                float v = acc[mi][ni][j];
                if (bias)  v += bias[cc];
                if (doRelu) v = fmaxf(v, 0.0f);
                if (addC)  v += addC[ro + cc];
                if (Cb) Cb[ro + cc] = f2b(v);
                else    C[ro + cc] = v;
            }
        }
    }
}

// ---------------- LayerNorm (wave per row, 4 rows/block) ----------------
static __global__ __launch_bounds__(256)
void ln_k(const float* __restrict__ in, const float* __restrict__ g,
          const float* __restrict__ b, float* __restrict__ out, int Dw, int nrows,
          unsigned short* __restrict__ outb,
          unsigned short* __restrict__ out2b, const int* __restrict__ idx2)
{
    const int row = blockIdx.x * 4 + (threadIdx.x >> 6);
    if (row >= nrows) return;
    const int lane = threadIdx.x & 63;
    const int per = Dw >> 6;
    float v[8];
    const float* rp = in + (long)row * Dw;
    float s = 0.f;
    for (int i = 0; i < per; ++i) { v[i] = rp[i * 64 + lane]; s += v[i]; }
    #pragma unroll
    for (int off = 32; off; off >>= 1) s += __shfl_xor(s, off, 64);
    const float mu = s / (float)Dw;
    float var = 0.f;
    for (int i = 0; i < per; ++i) { float d = v[i] - mu; var += d * d; }
    #pragma unroll
    for (int off = 32; off; off >>= 1) var += __shfl_xor(var, off, 64);
    const float rstd = rsqrtf(var / (float)Dw + 1e-5f);
    for (int i = 0; i < per; ++i) {
        int c = i * 64 + lane;
        float o = (v[i] - mu) * rstd * g[c] + b[c];
        out[(long)row * Dw + c] = o;
        if (outb)  outb[(long)row * Dw + c] = f2b(o);
        if (out2b) out2b[(long)idx2[row] * Dw + c] = f2b(o);
    }
}

// ---------------- node attention, CSR, 2-way unrolled ----------------
static __global__ __launch_bounds__(256)
void node_attn_csr_k(const unsigned short* __restrict__ qkv,
                     const unsigned short* __restrict__ lgb,
                     const int* __restrict__ goff, const int2* __restrict__ npack,
                     unsigned short* __restrict__ ob)
{
    int node = blockIdx.x * 4 + (threadIdx.x >> 6);
    if (node >= NN) return;
    const int lane = threadIdx.x & 63;
    float qv[8];
    {
        u16x8 q8 = *reinterpret_cast<const u16x8*>(qkv + (long)node * QKVW + lane * 8);
        #pragma unroll
        for (int i = 0; i < 8; ++i) qv[i] = b2f(q8[i]);
    }
    float wva[8] = {0.f, 0.f, 0.f, 0.f, 0.f, 0.f, 0.f, 0.f};
    float zac = 0.f;
    int j = goff[node];
    const int hi = (node + 1 < NN) ? goff[node + 1] : NE;
    const int eoffl = (lane & 7) * 8;

    for (; j + 2 <= hi; j += 2) {
        int2 pa = npack[j], pb = npack[j + 1];
        u16x8 kA = *reinterpret_cast<const u16x8*>(qkv + (long)pa.y * QKVW + 512 + lane * 8);
        u16x8 vA = *reinterpret_cast<const u16x8*>(qkv + (long)pa.y * QKVW + 1024 + lane * 8);
        u16x8 eA = *reinterpret_cast<const u16x8*>(lgb + (long)pa.x * ED + eoffl);
        u16x8 kB = *reinterpret_cast<const u16x8*>(qkv + (long)pb.y * QKVW + 512 + lane * 8);
        u16x8 vB = *reinterpret_cast<const u16x8*>(qkv + (long)pb.y * QKVW + 1024 + lane * 8);
        u16x8 eB = *reinterpret_cast<const u16x8*>(lgb + (long)pb.x * ED + eoffl);
        float edA[8], vvA[8], edB[8], vvB[8];
        float pA = 0.f, pB = 0.f;
        #pragma unroll
        for (int i = 0; i < 8; ++i) {
            edA[i] = b2f(eA[i]); vvA[i] = b2f(vA[i]);
            pA = fmaf(b2f(kA[i]) + edA[i], qv[i], pA);
            edB[i] = b2f(eB[i]); vvB[i] = b2f(vB[i]);
            pB = fmaf(b2f(kB[i]) + edB[i], qv[i], pB);
        }
        pA += __shfl_xor(pA, 1, 64); pA += __shfl_xor(pA, 2, 64); pA += __shfl_xor(pA, 4, 64);
        pB += __shfl_xor(pB, 1, 64); pB += __shfl_xor(pB, 2, 64); pB += __shfl_xor(pB, 4, 64);
        float wA = expf(fminf(fmaxf(pA * 0.125f, -10.0f), 10.0f));
        float wB = expf(fminf(fmaxf(pB * 0.125f, -10.0f), 10.0f));
        #pragma unroll
        for (int i = 0; i < 8; ++i) {
            wva[i] = fmaf(wA, vvA[i] + edA[i], wva[i]);
            wva[i] = fmaf(wB, vvB[i] + edB[i], wva[i]);
        }
        zac += wA + wB;
    }
    for (; j < hi; ++j) {
        int2 pa = npack[j];
        u16x8 kA = *reinterpret_cast<const u16x8*>(qkv + (long)pa.y * QKVW + 512 + lane * 8);
        u16x8 vA = *reinterpret_cast<const u16x8*>(qkv + (long)pa.y * QKVW + 1024 + lane * 8);
        u16x8 eA = *reinterpret_cast<const u16x8*>(lgb + (long)pa.x * ED + eoffl);
        float edA[8], vvA[8];
        float pA = 0.f;
        #pragma unroll
        for (int i = 0; i < 8; ++i) {
            edA[i] = b2f(eA[i]); vvA[i] = b2f(vA[i]);
            pA = fmaf(b2f(kA[i]) + edA[i], qv[i], pA);
        }
        pA += __shfl_xor(pA, 1, 64); pA += __shfl_xor(pA, 2, 64); pA += __shfl_xor(pA, 4, 64);
        float wA = expf(fminf(fmaxf(pA * 0.125f, -10.0f), 10.0f));
        #pragma unroll
        for (int i = 0; i < 8; ++i) wva[i] = fmaf(wA, vvA[i] + edA[i], wva[i]);
        zac += wA;
    }
    const float inv = 1.0f / fmaxf(zac, 1e-9f);
    u16x8 o8;
    #pragma unroll
    for (int i = 0; i < 8; ++i) o8[i] = f2b(wva[i] * inv);
    *reinterpret_cast<u16x8*>(ob + (long)node * DD + lane * 8) = o8;
}

// ---------------- line-graph attention, CSR, 4-way unrolled ----------------
static __global__ __launch_bounds__(256)
void lg_attn_csr_k(const unsigned short* __restrict__ qeb,
                   const unsigned short* __restrict__ keve,
                   const int* __restrict__ eoff, const int* __restrict__ esrc,
                   unsigned short* __restrict__ oeb)
{
    int d = blockIdx.x * 4 + (threadIdx.x >> 6);
    if (d >= NEL) return;
    const int lane = threadIdx.x & 63;
    const float qv = b2f(qeb[(long)d * ED + lane]);
    float oa = 0.f, zac = 0.f;
    int j = eoff[d];
    const int hi = (d + 1 < NEL) ? eoff[d + 1] : NLG;
    for (; j + 4 <= hi; j += 4) {
        int ss[4]; float kk[4], vv[4];
        #pragma unroll
        for (int u = 0; u < 4; ++u) ss[u] = esrc[j + u];
        #pragma unroll
        for (int u = 0; u < 4; ++u) {
            kk[u] = b2f(keve[(long)ss[u] * 128 + lane]);
            vv[u] = b2f(keve[(long)ss[u] * 128 + 64 + lane]);
        }
        #pragma unroll
        for (int u = 0; u < 4; ++u) {
            float p = kk[u] * qv;
            p += __shfl_xor(p, 1, 64); p += __shfl_xor(p, 2, 64); p += __shfl_xor(p, 4, 64);
            float w = expf(fminf(fmaxf(p * 0.35355339059327373f, -10.0f), 10.0f));
            oa = fmaf(w, vv[u], oa);
            zac += w;
        }
    }
    for (; j < hi; ++j) {
        int s = esrc[j];
        float kv = b2f(keve[(long)s * 128 + lane]);
        float vv = b2f(keve[(long)s * 128 + 64 + lane]);
        float p = kv * qv;
        p += __shfl_xor(p, 1, 64); p += __shfl_xor(p, 2, 64); p += __shfl_xor(p, 4, 64);
        float w = expf(fminf(fmaxf(p * 0.35355339059327373f, -10.0f), 10.0f));
        oa = fmaf(w, vv, oa);
        zac += w;
    }
    oeb[(long)d * ED + lane] = f2b(oa / fmaxf(zac, 1e-9f));
}

// ---------------- host ----------------
static inline void run_gemm(hipStream_t st, const unsigned short* A,
                            const unsigned short* Bt, const float* bias,
                            const float* addC, float* C, unsigned short* Cb,
                            int M, int K, int Nc, int relu, bool narrow)
{
    if (narrow) {
        dim3 g((Nc + 63) / 64, (M + 127) / 128);
        gemm_bf16_k<64><<<g, 256, 0, st>>>(A, nullptr, nullptr, Bt, bias, addC, C, Cb, M, K, Nc, relu, 0);
    } else {
        dim3 g((Nc + 127) / 128, (M + 127) / 128);
        gemm_bf16_k<128><<<g, 256, 0, st>>>(A, nullptr, nullptr, Bt, bias, addC, C, Cb, M, K, Nc, relu, 0);
    }
}
static inline void run_gemm2(hipStream_t st, const unsigned short* A1,
                             const unsigned short* A2, const int* idx2,
                             const unsigned short* Bt, const float* bias,
                             unsigned short* Cb, int M, int K, int Nc, int K1, bool narrow)
{
    if (narrow) {
        dim3 g((Nc + 63) / 64, (M + 127) / 128);
        gemm_bf16_k<64><<<g, 256, 0, st>>>(A1, A2, idx2, Bt, bias, nullptr, nullptr, Cb, M, K, Nc, 0, K1);
    } else {
        dim3 g((Nc + 127) / 128, (M + 127) / 128);
        gemm_bf16_k<128><<<g, 256, 0, st>>>(A1, A2, idx2, Bt, bias, nullptr, nullptr, Cb, M, K, Nc, 0, K1);
    }
}

extern "C" void kernel_launch(void* const* d_in, const int* in_sizes, int n_in,
                              void* d_out, int out_size, void* d_ws, size_t ws_size,
                              hipStream_t stream)
{
    const float* x_in  = (const float*)d_in[0];
    const float* rel   = (const float*)d_in[1];
    const float* Wq    = (const float*)d_in[2];
    const float* bq    = (const float*)d_in[3];
    const float* Wk    = (const float*)d_in[4];
    const float* Wv    = (const float*)d_in[5];
    const float* Wo    = (const float*)d_in[6];
    const float* bo    = (const float*)d_in[7];
    const float* ln1g  = (const float*)d_in[8];
    const float* ln1b  = (const float*)d_in[9];
    const float* F1    = (const float*)d_in[10];
    const float* f1b   = (const float*)d_in[11];
    const float* F2    = (const float*)d_in[12];
    const float* f2b_  = (const float*)d_in[13];
    const float* ln2g  = (const float*)d_in[14];
    const float* ln2b  = (const float*)d_in[15];
    const float* Eq    = (const float*)d_in[16];
    const float* eqb   = (const float*)d_in[17];
    const float* Ek    = (const float*)d_in[18];
    const float* Ev    = (const float*)d_in[19];
    const float* Eo    = (const float*)d_in[20];
    const float* eob   = (const float*)d_in[21];
    const float* Ns    = (const float*)d_in[22];
    const float* nsb   = (const float*)d_in[23];
    const float* Nd    = (const float*)d_in[24];
    const float* ndb   = (const float*)d_in[25];
    const float* eln1g = (const float*)d_in[26];
    const float* eln1b = (const float*)d_in[27];
    const float* G1    = (const float*)d_in[28];
    const float* g1b   = (const float*)d_in[29];
    const float* G2    = (const float*)d_in[30];
    const float* g2b   = (const float*)d_in[31];
    const float* eln2g = (const float*)d_in[32];
    const float* eln2b = (const float*)d_in[33];
    const int* edge_feat   = (const int*)d_in[34];
    const int* local_index = (const int*)d_in[35];
    const int* src_ids     = (const int*)d_in[36];
    const int* dst_ids     = (const int*)d_in[37];
    const int* g_src       = (const int*)d_in[38];
    const int* g_dst       = (const int*)d_in[39];
    const int* lg_src      = (const int*)d_in[40];
    const int* lg_dst      = (const int*)d_in[41];

    // outputs live in d_out
    float* xbuf = (float*)d_out;                   // (NN, DD)
    float* el   = xbuf + (size_t)NN * DD;          // (NEL, ED)

    // ---- workspace layout (~214 MB) ----
    float* W = (float*)d_ws;
    size_t off = 0;
    auto alloc = [&](size_t n) { float* p = W + off; off += (n + 63) & ~(size_t)63; return p; };
    float* t0  = alloc((size_t)NN * DD);
    float* t2  = alloc((size_t)NEL * ED);
    float* t3  = alloc((size_t)NEL * ED);
    float* qkvb = alloc((size_t)NL * QKVW);
    float* kvb  = alloc((size_t)NL * 128);
    float* qb2  = alloc((size_t)NL * ED);

    unsigned short* bp = (unsigned short*)(W + off);
    size_t boff = 0;
    auto balloc = [&](size_t n) { unsigned short* p = bp + boff; boff += (n + 63) & ~(size_t)63; return p; };
    unsigned short* lgb = balloc((size_t)NE * ED);
    unsigned short* xb  = balloc((size_t)NN * DD);
    unsigned short* qkv = balloc((size_t)NN * QKVW);
    unsigned short* elb = balloc((size_t)NEL * ED);
    unsigned short* e1b = balloc((size_t)NEL * ED);
    unsigned short* heb = balloc((size_t)NEL * ED);
    unsigned short* qeb = balloc((size_t)NEL * ED);
    unsigned short* fgb = balloc((size_t)NN * 4 * DD);
    unsigned short* hb   = qkv;
    unsigned short* keve = qkv + (size_t)NN * DD;
    unsigned short* ob   = fgb;
    unsigned short* WqkvT = balloc((size_t)NL * QKVW * DD);
    unsigned short* WoT  = balloc((size_t)NL * DD * DD);
    unsigned short* F1T  = balloc((size_t)NL * DD * 4 * DD);
    unsigned short* F2T  = balloc((size_t)NL * 4 * DD * DD);
    unsigned short* KVET = balloc((size_t)NL * 128 * 576);
    unsigned short* QET  = balloc((size_t)NL * 64 * 576);
    unsigned short* EoT  = balloc((size_t)NL * ED * ED);
    unsigned short* G1T  = balloc((size_t)NL * ED * 4 * ED);
    unsigned short* G2T  = balloc((size_t)NL * 4 * ED * ED);
    int* ip = (int*)(bp + ((boff + 63) & ~(size_t)63));
    size_t ioff = 0;
    auto ialloc = [&](size_t n) { int* p = ip + ioff; ioff += (n + 63) & ~(size_t)63; return p; };
    int* gcnt = ialloc(NN);
    int* goff = ialloc(NN);
    int* gcur = ialloc(NN);
    int* gord = ialloc(NE);
    int2* npack = (int2*)ialloc(2 * (size_t)NE);
    int* ecnt = ialloc(NEL);
    int* eoff = ialloc(NEL);
    int* ecur = ialloc(NEL);
    int* eord = ialloc(NLG);
    int* esrc = ialloc(NLG);
    int* bsum = ialloc(1024);

    // ---- weight prep ----
    auto tt = [&](const float* src, unsigned short* dst, int K, int N,
                  long lstride, int rowStride, int rowOff, int colOff) {
        dim3 g(K / 32, N / 32, NL);
        ttrans_k<<<g, 256, 0, stream>>>(src, dst, K, N, lstride, rowStride, rowOff, colOff);
    };
    tt(Wq, WqkvT, 512, 512, (long)QKVW * DD, DD, 0, 0);
    tt(Wk, WqkvT, 512, 512, (long)QKVW * DD, DD, 512, 0);
    tt(Wv, WqkvT, 512, 512, (long)QKVW * DD, DD, 1024, 0);
    tt(Wo, WoT, 512, 512, (long)DD * DD, DD, 0, 0);
    tt(F1, F1T, 512, 2048, (long)DD * 4 * DD, DD, 0, 0);
    tt(F2, F2T, 2048, 512, (long)4 * DD * DD, 4 * DD, 0, 0);
    tt(Ek, KVET, 64, 64, (long)128 * 576, 576, 0, 0);
    tt(Nd, KVET, 512, 64, (long)128 * 576, 576, 0, 64);
    tt(Ev, KVET, 64, 64, (long)128 * 576, 576, 64, 0);
    tt(Nd, KVET, 512, 64, (long)128 * 576, 576, 64, 64);
    tt(Eq, QET, 64, 64, (long)64 * 576, 576, 0, 0);
    tt(Ns, QET, 512, 64, (long)64 * 576, 576, 0, 64);
    tt(Eo, EoT, 64, 64, (long)ED * ED, ED, 0, 0);
    tt(G1, G1T, 64, 256, (long)ED * 4 * ED, ED, 0, 0);
    tt(G2, G2T, 256, 64, (long)4 * ED * ED, 4 * ED, 0, 0);
    build_qkvb_k<<<(NL * QKVW + 255) / 256, 256, 0, stream>>>(bq, qkvb);
    ebias_k<<<(NL * 128 + 255) / 256, 256, 0, stream>>>(ndb, eqb, nsb, kvb, qb2);

    // ---- CSR build ----
    const int nbG = (NN + 255) / 256, nbE = (NEL + 255) / 256;
    zero_k<<<nbG, 256, 0, stream>>>((float*)gcnt, NN);
    hist_k<<<(NE + 255) / 256, 256, 0, stream>>>(g_dst, gcnt, NE);
    scanA_k<<<nbG, 256, 0, stream>>>(gcnt, goff, bsum, NN);
    scanB_k<<<1, 1024, 0, stream>>>(bsum, nbG);
    scanC_k<<<nbG, 256, 0, stream>>>(bsum, goff, gcur, NN);
    scatter_k<<<(NE + 255) / 256, 256, 0, stream>>>(g_dst, gcur, gord, NE);
    zero_k<<<nbE, 256, 0, stream>>>((float*)ecnt, NEL);
    hist_k<<<(NLG + 255) / 256, 256, 0, stream>>>(lg_dst, ecnt, NLG);
    scanA_k<<<nbE, 256, 0, stream>>>(ecnt, eoff, bsum, NEL);
    scanB_k<<<1, 1024, 0, stream>>>(bsum, nbE);
    scanC_k<<<nbE, 256, 0, stream>>>(bsum, eoff, ecur, NEL);
    scatter_k<<<(NLG + 255) / 256, 256, 0, stream>>>(lg_dst, ecur, eord, NLG);
    pack_k<<<(NLG + 255) / 256, 256, 0, stream>>>(gord, g_src, eord, lg_src, npack, esrc);

    const int ndD = NN * DD;
    const int elD = NEL * ED;
    castcopy_k<<<(ndD + 255) / 256, 256, 0, stream>>>(x_in, xbuf, xb, ndD);
    init_lg_k<<<(NE * ED + 255) / 256, 256, 0, stream>>>(rel, edge_feat, lgb);
    gather64_k<<<(elD + 255) / 256, 256, 0, stream>>>(lgb, local_index, el, elb);

    for (int i = 0; i < NL; ++i) {
        size_t oD2 = (size_t)i * DD * DD, oE2 = (size_t)i * ED * ED;

        // ---- node attention (reads lgb BEFORE this layer's edge update) ----
        run_gemm(stream, xb, WqkvT + (size_t)i * QKVW * DD, qkvb + (size_t)i * QKVW,
                 nullptr, nullptr, qkv, NN, DD, QKVW, 0, false);
        node_attn_csr_k<<<NN / 4, 256, 0, stream>>>(qkv, lgb, goff, npack, ob);
        run_gemm(stream, ob, WoT + oD2, bo + (size_t)i * DD, xbuf, t0, nullptr, NN, DD, DD, 0, true);
        ln_k<<<(NN + 3) / 4, 256, 0, stream>>>(t0, ln1g + (size_t)i * DD, ln1b + (size_t)i * DD,
                                               t0, DD, NN, hb, nullptr, nullptr);

        // ---- edge branch (fused split-K GEMMs) ----
        run_gemm2(stream, elb, xb, dst_ids, KVET + (size_t)i * 128 * 576,
                  kvb + (size_t)i * 128, keve, NEL, 576, 128, 64, true);
        run_gemm2(stream, elb, xb, src_ids, QET + (size_t)i * 64 * 576,
                  qb2 + (size_t)i * 64, qeb, NEL, 576, 64, 64, true);
        lg_attn_csr_k<<<NEL / 4, 256, 0, stream>>>(qeb, keve, eoff, esrc, e1b);
        run_gemm(stream, e1b, EoT + oE2, eob + (size_t)i * ED, el, t2, nullptr, NEL, ED, ED, 0, true);
        ln_k<<<(NEL + 3) / 4, 256, 0, stream>>>(t2, eln1g + (size_t)i * ED, eln1b + (size_t)i * ED,
                                                t2, ED, NEL, heb, nullptr, nullptr);
        run_gemm(stream, heb, G1T + (size_t)i * ED * 4 * ED, g1b + (size_t)i * 4 * ED,
                 nullptr, nullptr, fgb, NEL, ED, 4 * ED, 1, false);
        run_gemm(stream, fgb, G2T + (size_t)i * 4 * ED * ED, g2b + (size_t)i * ED,
                 t2, t3, nullptr, NEL, 4 * ED, ED, 0, true);
        ln_k<<<(NEL + 3) / 4, 256, 0, stream>>>(t3, eln2g + (size_t)i * ED, eln2b + (size_t)i * ED,
                                                el, ED, NEL, elb, lgb, local_index);

        // ---- node FFN ----
        run_gemm(stream, hb, F1T + (size_t)i * DD * 4 * DD, f1b + (size_t)i * 4 * DD,
                 nullptr, nullptr, fgb, NN, DD, 4 * DD, 1, false);
        run_gemm(stream, fgb, F2T + (size_t)i * 4 * DD * DD, f2b_ + (size_t)i * DD,
                 t0, xbuf, nullptr, NN, 2048, DD, 0, true);
        ln_k<<<(NN + 3) / 4, 256, 0, stream>>>(xbuf, ln2g + (size_t)i * DD, ln2b + (size_t)i * DD,
                                               xbuf, DD, NN, xb, nullptr, nullptr);
    }
    // outputs already in d_out
}

// Round 9
// 2174.614 us; speedup vs baseline: 1.0261x; 1.0261x over previous
//
#include <hip/hip_runtime.h>
#include <math.h>

#define NN   10000      // nodes
#define DD   512        // node dim
#define NH   8          // node heads (DK=64)
#define NE   120000     // edges (global)
#define NEL  60000      // local edges
#define NLG  600000     // line-graph edges
#define ED   64         // edge dim (EH=8, EDK=8)
#define NEH  8
#define NL   4          // layers
#define QKVW 1536       // fused q|k|v row width

typedef __attribute__((ext_vector_type(8))) short bf16x8;
typedef __attribute__((ext_vector_type(8))) unsigned short u16x8;
typedef __attribute__((ext_vector_type(4))) float f32x4;

__device__ __forceinline__ unsigned short f2b(float f) {
    union { float f; unsigned u; } c; c.f = f;
    unsigned u = c.u;
    unsigned r = u + 0x7FFFu + ((u >> 16) & 1u);
    return (unsigned short)(r >> 16);
}
__device__ __forceinline__ float b2f(unsigned short b) {
    union { unsigned u; float f; } c; c.u = ((unsigned)b) << 16;
    return c.f;
}

// async global->LDS, 16B per lane; LDS dest is wave-uniform base + lane*16 (HW)
__device__ __forceinline__ void gl16(const unsigned short* g, unsigned short* l) {
    __builtin_amdgcn_global_load_lds(
        (const __attribute__((address_space(1))) unsigned int*)g,
        (__attribute__((address_space(3))) unsigned int*)l, 16, 0, 0);
}

// ---------------- elementwise helpers ----------------
static __global__ __launch_bounds__(256)
void zero_k(float* __restrict__ p, int n) {
    int i = blockIdx.x * 256 + threadIdx.x;
    if (i < n) p[i] = 0.0f;
}

static __global__ __launch_bounds__(256)
void castcopy_k(const float* __restrict__ s, float* __restrict__ d,
                unsigned short* __restrict__ db, int n) {
    int i = blockIdx.x * 256 + threadIdx.x;
    if (i < n) { float v = s[i]; if (d) d[i] = v; db[i] = f2b(v); }
}

static __global__ __launch_bounds__(256)
void init_lg_k(const float* __restrict__ rel, const int* __restrict__ ef,
               unsigned short* __restrict__ lgb) {
    int i = blockIdx.x * 256 + threadIdx.x;
    if (i >= NE * ED) return;
    int e = i >> 6, c = i & 63;
    lgb[i] = f2b(rel[ef[e] * ED + c]);
}

static __global__ __launch_bounds__(256)
void gather64_k(const unsigned short* __restrict__ lgb, const int* __restrict__ idx,
                float* __restrict__ el, unsigned short* __restrict__ elb) {
    int i = blockIdx.x * 256 + threadIdx.x;
    if (i >= NEL * ED) return;
    int r = i >> 6;
    unsigned short b = lgb[(long)idx[r] * ED + (i & 63)];
    el[i] = b2f(b); elb[i] = b;
}

// ---------------- LDS-tiled transpose+cast ----------------
static __global__ __launch_bounds__(256)
void ttrans_k(const float* __restrict__ in, unsigned short* __restrict__ out,
              int K, int N, long lstride, int rowStride, int rowOff, int colOff) {
    __shared__ float sm[32][33];
    const int l = blockIdx.z;
    const int kt = blockIdx.x * 32, nt = blockIdx.y * 32;
    const int tx = threadIdx.x & 31, ty = threadIdx.x >> 5;
    const float* ip = in + (size_t)l * K * N;
    #pragma unroll
    for (int r = 0; r < 4; ++r)
        sm[ty + 8 * r][tx] = ip[(size_t)(kt + ty + 8 * r) * N + nt + tx];
    __syncthreads();
    unsigned short* op = out + (size_t)l * lstride;
    #pragma unroll
    for (int r = 0; r < 4; ++r) {
        int n = nt + ty + 8 * r;
        op[(size_t)(rowOff + n) * rowStride + colOff + kt + tx] = f2b(sm[tx][ty + 8 * r]);
    }
}

static __global__ __launch_bounds__(256)
void build_qkvb_k(const float* __restrict__ bq, float* __restrict__ out) {
    int i = blockIdx.x * 256 + threadIdx.x;
    if (i >= NL * QKVW) return;
    int l = i / QKVW, c = i - l * QKVW;
    out[i] = (c < 512) ? bq[l * 512 + c] : 0.0f;
}

static __global__ __launch_bounds__(256)
void ebias_k(const float* __restrict__ ndb, const float* __restrict__ eqb,
             const float* __restrict__ nsb, float* __restrict__ kvb,
             float* __restrict__ qb2) {
    int i = blockIdx.x * 256 + threadIdx.x;
    if (i < NL * 128) kvb[i] = ndb[(i >> 7) * 64 + (i & 63)];
    if (i < NL * 64)  qb2[i] = eqb[i] + nsb[i];
}

// ---------------- CSR build ----------------
static __global__ __launch_bounds__(256)
void hist_k(const int* __restrict__ dst, int* __restrict__ cnt, int n) {
    int i = blockIdx.x * 256 + threadIdx.x;
    if (i < n) atomicAdd(&cnt[dst[i]], 1);
}

static __global__ __launch_bounds__(256)
void scanA_k(const int* __restrict__ cnt, int* __restrict__ off,
             int* __restrict__ bsum, int n) {
    __shared__ int sm[256];
    const int t = threadIdx.x;
    const int i = blockIdx.x * 256 + t;
    int v = (i < n) ? cnt[i] : 0;
    sm[t] = v; __syncthreads();
    int x = v;
    #pragma unroll
    for (int d = 1; d < 256; d <<= 1) {
        int y = (t >= d) ? sm[t - d] : 0;
        __syncthreads();
        x += y; sm[t] = x; __syncthreads();
    }
    if (i < n) off[i] = x - v;
    if (t == 255) bsum[blockIdx.x] = x;
}

static __global__ __launch_bounds__(1024)
void scanB_k(int* __restrict__ bsum, int nb) {
    __shared__ int sm[1024];
    const int t = threadIdx.x;
    int v = (t < nb) ? bsum[t] : 0;
    sm[t] = v; __syncthreads();
    int x = v;
    #pragma unroll
    for (int d = 1; d < 1024; d <<= 1) {
        int y = (t >= d) ? sm[t - d] : 0;
        __syncthreads();
        x += y; sm[t] = x; __syncthreads();
    }
    if (t < nb) bsum[t] = x - v;
}

static __global__ __launch_bounds__(256)
void scanC_k(const int* __restrict__ bsum, int* __restrict__ off,
             int* __restrict__ cur, int n) {
    int i = blockIdx.x * 256 + threadIdx.x;
    if (i < n) { int o = off[i] + bsum[blockIdx.x]; off[i] = o; cur[i] = o; }
}

static __global__ __launch_bounds__(256)
void scatter_k(const int* __restrict__ dst, int* __restrict__ cur,
               int* __restrict__ ord, int n) {
    int i = blockIdx.x * 256 + threadIdx.x;
    if (i < n) { int p = atomicAdd(&cur[dst[i]], 1); ord[p] = i; }
}

static __global__ __launch_bounds__(256)
void pack_k(const int* __restrict__ gord, const int* __restrict__ gsrc,
            const int* __restrict__ eord, const int* __restrict__ lsrc,
            int2* __restrict__ npack, int* __restrict__ esrc) {
    int i = blockIdx.x * 256 + threadIdx.x;
    if (i < NE) { int e = gord[i]; npack[i] = make_int2(e, gsrc[e]); }
    if (i < NLG) esrc[i] = lsrc[eord[i]];
}

// ---------------- bf16 MFMA GEMM: m97 structure ----------------------------
// BK=32, SINGLE-buffered LDS (16KB/12KB -> 8 blocks/CU), global_load_lds w16,
// 2 barriers per K-tile; barrier-drain stall hidden by cross-block overlap.
// LDS[r][s] = src[r][s ^ f(r)], f(r)=(r&3)^((r>>2)&3): conflict-free both sides.
// If A2==null: C = A[M,K] @ Bt[Nc,K]^T; else A-row r = [A[r][0:K1] | A2[idx2[r]][:]]
template<int BN>
static __global__ __launch_bounds__(256)
void gemm_bf16_k(const unsigned short* __restrict__ A,
                 const unsigned short* __restrict__ A2, const int* __restrict__ idx2,
                 const unsigned short* __restrict__ Bt, const float* __restrict__ bias,
                 const float* __restrict__ addC, float* __restrict__ C,
                 unsigned short* __restrict__ Cb,
                 int M, int K, int Nc, int doRelu, int K1)
{
    constexpr int NI = BN / 32;               // col frags per wave
    __shared__ unsigned short Asl[128 * 32];
    __shared__ unsigned short Bsl[BN * 32];
    const int tid  = threadIdx.x;
    const int lane = tid & 63;
    const int wave = tid >> 6;
    const int wr = (wave >> 1) * 64;
    const int wc = (wave & 1) * (BN / 2);

    // XCD-aware bijective block swizzle (m204)
    const int nwg = gridDim.x * gridDim.y;
    const int hw = blockIdx.y * gridDim.x + blockIdx.x;
    const int q8 = nwg >> 3, r8 = nwg & 7;
    const int xcd = hw & 7, rest = hw >> 3;
    const int logical = (xcd < r8 ? xcd * (q8 + 1) : r8 * (q8 + 1) + (xcd - r8) * q8) + rest;
    const int bm = (logical / gridDim.x) * 128;
    const int bn = (logical % gridDim.x) * BN;

    // staging geometry: one gl16 covers 16 rows x 32 cols (1KB); lane -> row rl, slot sl
    const int rl = lane >> 2;                 // 0..15
    const int sl = lane & 3;
    #define FSWZ(r) (((r) & 3) ^ (((r) >> 2) & 3))
    // A rows owned by this thread (2 gl16 per wave => rows wave*32 + rl, +16)
    const int ar0 = wave * 32 + rl, ar1 = ar0 + 16;
    const int ga0 = bm + ar0, ga1 = bm + ar1;
    const bool av0 = ga0 < M, av1 = ga1 < M;
    long ia0 = 0, ia1 = 0;
    if (A2) { if (av0) ia0 = idx2[ga0]; if (av1) ia1 = idx2[ga1]; }
    const int ac0 = (sl ^ FSWZ(ar0)) * 8;     // pre-swizzled source col (elems)
    const int ac1 = (sl ^ FSWZ(ar1)) * 8;
    // B rows
    const int br0 = wave * (BN / 4) + rl;
    const int br1 = br0 + 16;                 // used only for BN==128
    const int bc0 = (sl ^ FSWZ(br0)) * 8;
    const int bc1 = (sl ^ FSWZ(br1)) * 8;

    auto stage = [&](int k0) {
        const unsigned short *s0, *s1;
        if (!A2) {
            s0 = A + (long)ga0 * K + k0 + ac0;
            s1 = A + (long)ga1 * K + k0 + ac1;
        } else if (k0 < K1) {
            s0 = A + (long)ga0 * K1 + k0 + ac0;
            s1 = A + (long)ga1 * K1 + k0 + ac1;
        } else {
            s0 = A2 + ia0 * DD + (k0 - K1) + ac0;
            s1 = A2 + ia1 * DD + (k0 - K1) + ac1;
        }
        if (av0) gl16(s0, Asl + (wave * 32) * 32);
        if (av1) gl16(s1, Asl + (wave * 32 + 16) * 32);
        gl16(Bt + (long)(bn + br0) * K + k0 + bc0, Bsl + (wave * (BN / 4)) * 32);
        if (BN == 128)
            gl16(Bt + (long)(bn + br1) * K + k0 + bc1, Bsl + (wave * 32 + 16) * 32);
    };

    f32x4 acc[4][NI] = {};
    const int rbase = lane & 15;
    const int ks = lane >> 4;

    for (int k0 = 0; k0 < K; k0 += 32) {
        stage(k0);
        __syncthreads();                      // staged tile landed (vmcnt drained)
        bf16x8 af[4]; bf16x8 bfr[NI];
        #pragma unroll
        for (int mi = 0; mi < 4; ++mi) {
            int r = wr + mi * 16 + rbase;
            int s = ks ^ FSWZ(r);
            af[mi] = *reinterpret_cast<const bf16x8*>(Asl + r * 32 + s * 8);
        }
        #pragma unroll
        for (int ni = 0; ni < NI; ++ni) {
            int r = wc + ni * 16 + rbase;
            int s = ks ^ FSWZ(r);
            bfr[ni] = *reinterpret_cast<const bf16x8*>(Bsl + r * 32 + s * 8);
        }
        #pragma unroll
        for (int mi = 0; mi < 4; ++mi)
            #pragma unroll
            for (int ni = 0; ni < NI; ++ni)
                acc[mi][ni] = __builtin_amdgcn_mfma_f32_16x16x32_bf16(
                    af[mi], bfr[ni], acc[mi][ni], 0, 0, 0);
        __syncthreads();                      // ds_reads done before re-stage
    }
    #undef FSWZ

    const int colBase = bn + wc + rbase;
    const int rowBase = bm + wr + ks * 4;
    #pragma unroll
    for (int mi = 0; mi < 4; ++mi) {
        #pragma unroll
        for (int j = 0; j < 4; ++j) {
            int r = rowBase + mi * 16 + j;
            if (r >= M) continue;
            long ro = (long)r * Nc;
            #pragma unroll
            for (int ni = 0; ni < NI; ++ni) {
                int cc = colBase + ni * 16;
                if (cc >= Nc) continue;
                float v = acc[mi][ni][j];
                if (bias)  v += bias[cc];
                if (doRelu) v = fmaxf(v, 0.0f);
                if (addC)  v += addC[ro + cc];
                if (Cb) Cb[ro + cc] = f2b(v);
                else    C[ro + cc] = v;
            }
        }
    }
}

// ---------------- LayerNorm (wave per row, 4 rows/block) ----------------
static __global__ __launch_bounds__(256)
void ln_k(const float* __restrict__ in, const float* __restrict__ g,
          const float* __restrict__ b, float* __restrict__ out, int Dw, int nrows,
          unsigned short* __restrict__ outb,
          unsigned short* __restrict__ out2b, const int* __restrict__ idx2)
{
    const int row = blockIdx.x * 4 + (threadIdx.x >> 6);
    if (row >= nrows) return;
    const int lane = threadIdx.x & 63;
    const int per = Dw >> 6;
    float v[8];
    const float* rp = in + (long)row * Dw;
    float s = 0.f;
    for (int i = 0; i < per; ++i) { v[i] = rp[i * 64 + lane]; s += v[i]; }
    #pragma unroll
    for (int off = 32; off; off >>= 1) s += __shfl_xor(s, off, 64);
    const float mu = s / (float)Dw;
    float var = 0.f;
    for (int i = 0; i < per; ++i) { float d = v[i] - mu; var += d * d; }
    #pragma unroll
    for (int off = 32; off; off >>= 1) var += __shfl_xor(var, off, 64);
    const float rstd = rsqrtf(var / (float)Dw + 1e-5f);
    for (int i = 0; i < per; ++i) {
        int c = i * 64 + lane;
        float o = (v[i] - mu) * rstd * g[c] + b[c];
        out[(long)row * Dw + c] = o;
        if (outb)  outb[(long)row * Dw + c] = f2b(o);
        if (out2b) out2b[(long)idx2[row] * Dw + c] = f2b(o);
    }
}

// ---------------- node attention, CSR, 2-way unrolled ----------------
static __global__ __launch_bounds__(256)
void node_attn_csr_k(const unsigned short* __restrict__ qkv,
                     const unsigned short* __restrict__ lgb,
                     const int* __restrict__ goff, const int2* __restrict__ npack,
                     unsigned short* __restrict__ ob)
{
    int node = blockIdx.x * 4 + (threadIdx.x >> 6);
    if (node >= NN) return;
    const int lane = threadIdx.x & 63;
    float qv[8];
    {
        u16x8 q8 = *reinterpret_cast<const u16x8*>(qkv + (long)node * QKVW + lane * 8);
        #pragma unroll
        for (int i = 0; i < 8; ++i) qv[i] = b2f(q8[i]);
    }
    float wva[8] = {0.f, 0.f, 0.f, 0.f, 0.f, 0.f, 0.f, 0.f};
    float zac = 0.f;
    int j = goff[node];
    const int hi = (node + 1 < NN) ? goff[node + 1] : NE;
    const int eoffl = (lane & 7) * 8;

    for (; j + 2 <= hi; j += 2) {
        int2 pa = npack[j], pb = npack[j + 1];
        u16x8 kA = *reinterpret_cast<const u16x8*>(qkv + (long)pa.y * QKVW + 512 + lane * 8);
        u16x8 vA = *reinterpret_cast<const u16x8*>(qkv + (long)pa.y * QKVW + 1024 + lane * 8);
        u16x8 eA = *reinterpret_cast<const u16x8*>(lgb + (long)pa.x * ED + eoffl);
        u16x8 kB = *reinterpret_cast<const u16x8*>(qkv + (long)pb.y * QKVW + 512 + lane * 8);
        u16x8 vB = *reinterpret_cast<const u16x8*>(qkv + (long)pb.y * QKVW + 1024 + lane * 8);
        u16x8 eB = *reinterpret_cast<const u16x8*>(lgb + (long)pb.x * ED + eoffl);
        float edA[8], vvA[8], edB[8], vvB[8];
        float pA = 0.f, pB = 0.f;
        #pragma unroll
        for (int i = 0; i < 8; ++i) {
            edA[i] = b2f(eA[i]); vvA[i] = b2f(vA[i]);
            pA = fmaf(b2f(kA[i]) + edA[i], qv[i], pA);
            edB[i] = b2f(eB[i]); vvB[i] = b2f(vB[i]);
            pB = fmaf(b2f(kB[i]) + edB[i], qv[i], pB);
        }
        pA += __shfl_xor(pA, 1, 64); pA += __shfl_xor(pA, 2, 64); pA += __shfl_xor(pA, 4, 64);
        pB += __shfl_xor(pB, 1, 64); pB += __shfl_xor(pB, 2, 64); pB += __shfl_xor(pB, 4, 64);
        float wA = expf(fminf(fmaxf(pA * 0.125f, -10.0f), 10.0f));
        float wB = expf(fminf(fmaxf(pB * 0.125f, -10.0f), 10.0f));
        #pragma unroll
        for (int i = 0; i < 8; ++i) {
            wva[i] = fmaf(wA, vvA[i] + edA[i], wva[i]);
            wva[i] = fmaf(wB, vvB[i] + edB[i], wva[i]);
        }
        zac += wA + wB;
    }
    for (; j < hi; ++j) {
        int2 pa = npack[j];
        u16x8 kA = *reinterpret_cast<const u16x8*>(qkv + (long)pa.y * QKVW + 512 + lane * 8);
        u16x8 vA = *reinterpret_cast<const u16x8*>(qkv + (long)pa.y * QKVW + 1024 + lane * 8);
        u16x8 eA = *reinterpret_cast<const u16x8*>(lgb + (long)pa.x * ED + eoffl);
        float edA[8], vvA[8];
        float pA = 0.f;
        #pragma unroll
        for (int i = 0; i < 8; ++i) {
            edA[i] = b2f(eA[i]); vvA[i] = b2f(vA[i]);
            pA = fmaf(b2f(kA[i]) + edA[i], qv[i], pA);
        }
        pA += __shfl_xor(pA, 1, 64); pA += __shfl_xor(pA, 2, 64); pA += __shfl_xor(pA, 4, 64);
        float wA = expf(fminf(fmaxf(pA * 0.125f, -10.0f), 10.0f));
        #pragma unroll
        for (int i = 0; i < 8; ++i) wva[i] = fmaf(wA, vvA[i] + edA[i], wva[i]);
        zac += wA;
    }
    const float inv = 1.0f / fmaxf(zac, 1e-9f);
    u16x8 o8;
    #pragma unroll
    for (int i = 0; i < 8; ++i) o8[i] = f2b(wva[i] * inv);
    *reinterpret_cast<u16x8*>(ob + (long)node * DD + lane * 8) = o8;
}

// ---------------- line-graph attention, CSR, 4-way unrolled ----------------
static __global__ __launch_bounds__(256)
void lg_attn_csr_k(const unsigned short* __restrict__ qeb,
                   const unsigned short* __restrict__ keve,
                   const int* __restrict__ eoff, const int* __restrict__ esrc,
                   unsigned short* __restrict__ oeb)
{
    int d = blockIdx.x * 4 + (threadIdx.x >> 6);
    if (d >= NEL) return;
    const int lane = threadIdx.x & 63;
    const float qv = b2f(qeb[(long)d * ED + lane]);
    float oa = 0.f, zac = 0.f;
    int j = eoff[d];
    const int hi = (d + 1 < NEL) ? eoff[d + 1] : NLG;
    for (; j + 4 <= hi; j += 4) {
        int ss[4]; float kk[4], vv[4];
        #pragma unroll
        for (int u = 0; u < 4; ++u) ss[u] = esrc[j + u];
        #pragma unroll
        for (int u = 0; u < 4; ++u) {
            kk[u] = b2f(keve[(long)ss[u] * 128 + lane]);
            vv[u] = b2f(keve[(long)ss[u] * 128 + 64 + lane]);
        }
        #pragma unroll
        for (int u = 0; u < 4; ++u) {
            float p = kk[u] * qv;
            p += __shfl_xor(p, 1, 64); p += __shfl_xor(p, 2, 64); p += __shfl_xor(p, 4, 64);
            float w = expf(fminf(fmaxf(p * 0.35355339059327373f, -10.0f), 10.0f));
            oa = fmaf(w, vv[u], oa);
            zac += w;
        }
    }
    for (; j < hi; ++j) {
        int s = esrc[j];
        float kv = b2f(keve[(long)s * 128 + lane]);
        float vv = b2f(keve[(long)s * 128 + 64 + lane]);
        float p = kv * qv;
        p += __shfl_xor(p, 1, 64); p += __shfl_xor(p, 2, 64); p += __shfl_xor(p, 4, 64);
        float w = expf(fminf(fmaxf(p * 0.35355339059327373f, -10.0f), 10.0f));
        oa = fmaf(w, vv, oa);
        zac += w;
    }
    oeb[(long)d * ED + lane] = f2b(oa / fmaxf(zac, 1e-9f));
}

// ---------------- host ----------------
static inline void run_gemm(hipStream_t st, const unsigned short* A,
                            const unsigned short* Bt, const float* bias,
                            const float* addC, float* C, unsigned short* Cb,
                            int M, int K, int Nc, int relu, bool narrow)
{
    if (narrow) {
        dim3 g((Nc + 63) / 64, (M + 127) / 128);
        gemm_bf16_k<64><<<g, 256, 0, st>>>(A, nullptr, nullptr, Bt, bias, addC, C, Cb, M, K, Nc, relu, 0);
    } else {
        dim3 g((Nc + 127) / 128, (M + 127) / 128);
        gemm_bf16_k<128><<<g, 256, 0, st>>>(A, nullptr, nullptr, Bt, bias, addC, C, Cb, M, K, Nc, relu, 0);
    }
}
static inline void run_gemm2(hipStream_t st, const unsigned short* A1,
                             const unsigned short* A2, const int* idx2,
                             const unsigned short* Bt, const float* bias,
                             unsigned short* Cb, int M, int K, int Nc, int K1, bool narrow)
{
    if (narrow) {
        dim3 g((Nc + 63) / 64, (M + 127) / 128);
        gemm_bf16_k<64><<<g, 256, 0, st>>>(A1, A2, idx2, Bt, bias, nullptr, nullptr, Cb, M, K, Nc, 0, K1);
    } else {
        dim3 g((Nc + 127) / 128, (M + 127) / 128);
        gemm_bf16_k<128><<<g, 256, 0, st>>>(A1, A2, idx2, Bt, bias, nullptr, nullptr, Cb, M, K, Nc, 0, K1);
    }
}

extern "C" void kernel_launch(void* const* d_in, const int* in_sizes, int n_in,
                              void* d_out, int out_size, void* d_ws, size_t ws_size,
                              hipStream_t stream)
{
    const float* x_in  = (const float*)d_in[0];
    const float* rel   = (const float*)d_in[1];
    const float* Wq    = (const float*)d_in[2];
    const float* bq    = (const float*)d_in[3];
    const float* Wk    = (const float*)d_in[4];
    const float* Wv    = (const float*)d_in[5];
    const float* Wo    = (const float*)d_in[6];
    const float* bo    = (const float*)d_in[7];
    const float* ln1g  = (const float*)d_in[8];
    const float* ln1b  = (const float*)d_in[9];
    const float* F1    = (const float*)d_in[10];
    const float* f1b   = (const float*)d_in[11];
    const float* F2    = (const float*)d_in[12];
    const float* f2b_  = (const float*)d_in[13];
    const float* ln2g  = (const float*)d_in[14];
    const float* ln2b  = (const float*)d_in[15];
    const float* Eq    = (const float*)d_in[16];
    const float* eqb   = (const float*)d_in[17];
    const float* Ek    = (const float*)d_in[18];
    const float* Ev    = (const float*)d_in[19];
    const float* Eo    = (const float*)d_in[20];
    const float* eob   = (const float*)d_in[21];
    const float* Ns    = (const float*)d_in[22];
    const float* nsb   = (const float*)d_in[23];
    const float* Nd    = (const float*)d_in[24];
    const float* ndb   = (const float*)d_in[25];
    const float* eln1g = (const float*)d_in[26];
    const float* eln1b = (const float*)d_in[27];
    const float* G1    = (const float*)d_in[28];
    const float* g1b   = (const float*)d_in[29];
    const float* G2    = (const float*)d_in[30];
    const float* g2b   = (const float*)d_in[31];
    const float* eln2g = (const float*)d_in[32];
    const float* eln2b = (const float*)d_in[33];
    const int* edge_feat   = (const int*)d_in[34];
    const int* local_index = (const int*)d_in[35];
    const int* src_ids     = (const int*)d_in[36];
    const int* dst_ids     = (const int*)d_in[37];
    const int* g_src       = (const int*)d_in[38];
    const int* g_dst       = (const int*)d_in[39];
    const int* lg_src      = (const int*)d_in[40];
    const int* lg_dst      = (const int*)d_in[41];

    // outputs live in d_out
    float* xbuf = (float*)d_out;                   // (NN, DD)
    float* el   = xbuf + (size_t)NN * DD;          // (NEL, ED)

    // ---- workspace layout (~214 MB) ----
    float* W = (float*)d_ws;
    size_t off = 0;
    auto alloc = [&](size_t n) { float* p = W + off; off += (n + 63) & ~(size_t)63; return p; };
    float* t0  = alloc((size_t)NN * DD);
    float* t2  = alloc((size_t)NEL * ED);
    float* t3  = alloc((size_t)NEL * ED);
    float* qkvb = alloc((size_t)NL * QKVW);
    float* kvb  = alloc((size_t)NL * 128);
    float* qb2  = alloc((size_t)NL * ED);

    unsigned short* bp = (unsigned short*)(W + off);
    size_t boff = 0;
    auto balloc = [&](size_t n) { unsigned short* p = bp + boff; boff += (n + 63) & ~(size_t)63; return p; };
    unsigned short* lgb = balloc((size_t)NE * ED);
    unsigned short* xb  = balloc((size_t)NN * DD);
    unsigned short* qkv = balloc((size_t)NN * QKVW);
    unsigned short* elb = balloc((size_t)NEL * ED);
    unsigned short* e1b = balloc((size_t)NEL * ED);
    unsigned short* heb = balloc((size_t)NEL * ED);
    unsigned short* qeb = balloc((size_t)NEL * ED);
    unsigned short* fgb = balloc((size_t)NN * 4 * DD);
    unsigned short* hb   = qkv;
    unsigned short* keve = qkv + (size_t)NN * DD;
    unsigned short* ob   = fgb;
    unsigned short* WqkvT = balloc((size_t)NL * QKVW * DD);
    unsigned short* WoT  = balloc((size_t)NL * DD * DD);
    unsigned short* F1T  = balloc((size_t)NL * DD * 4 * DD);
    unsigned short* F2T  = balloc((size_t)NL * 4 * DD * DD);
    unsigned short* KVET = balloc((size_t)NL * 128 * 576);
    unsigned short* QET  = balloc((size_t)NL * 64 * 576);
    unsigned short* EoT  = balloc((size_t)NL * ED * ED);
    unsigned short* G1T  = balloc((size_t)NL * ED * 4 * ED);
    unsigned short* G2T  = balloc((size_t)NL * 4 * ED * ED);
    int* ip = (int*)(bp + ((boff + 63) & ~(size_t)63));
    size_t ioff = 0;
    auto ialloc = [&](size_t n) { int* p = ip + ioff; ioff += (n + 63) & ~(size_t)63; return p; };
    int* gcnt = ialloc(NN);
    int* goff = ialloc(NN);
    int* gcur = ialloc(NN);
    int* gord = ialloc(NE);
    int2* npack = (int2*)ialloc(2 * (size_t)NE);
    int* ecnt = ialloc(NEL);
    int* eoff = ialloc(NEL);
    int* ecur = ialloc(NEL);
    int* eord = ialloc(NLG);
    int* esrc = ialloc(NLG);
    int* bsum = ialloc(1024);

    // ---- weight prep ----
    auto tt = [&](const float* src, unsigned short* dst, int K, int N,
                  long lstride, int rowStride, int rowOff, int colOff) {
        dim3 g(K / 32, N / 32, NL);
        ttrans_k<<<g, 256, 0, stream>>>(src, dst, K, N, lstride, rowStride, rowOff, colOff);
    };
    tt(Wq, WqkvT, 512, 512, (long)QKVW * DD, DD, 0, 0);
    tt(Wk, WqkvT, 512, 512, (long)QKVW * DD, DD, 512, 0);
    tt(Wv, WqkvT, 512, 512, (long)QKVW * DD, DD, 1024, 0);
    tt(Wo, WoT, 512, 512, (long)DD * DD, DD, 0, 0);
    tt(F1, F1T, 512, 2048, (long)DD * 4 * DD, DD, 0, 0);
    tt(F2, F2T, 2048, 512, (long)4 * DD * DD, 4 * DD, 0, 0);
    tt(Ek, KVET, 64, 64, (long)128 * 576, 576, 0, 0);
    tt(Nd, KVET, 512, 64, (long)128 * 576, 576, 0, 64);
    tt(Ev, KVET, 64, 64, (long)128 * 576, 576, 64, 0);
    tt(Nd, KVET, 512, 64, (long)128 * 576, 576, 64, 64);
    tt(Eq, QET, 64, 64, (long)64 * 576, 576, 0, 0);
    tt(Ns, QET, 512, 64, (long)64 * 576, 576, 0, 64);
    tt(Eo, EoT, 64, 64, (long)ED * ED, ED, 0, 0);
    tt(G1, G1T, 64, 256, (long)ED * 4 * ED, ED, 0, 0);
    tt(G2, G2T, 256, 64, (long)4 * ED * ED, 4 * ED, 0, 0);
    build_qkvb_k<<<(NL * QKVW + 255) / 256, 256, 0, stream>>>(bq, qkvb);
    ebias_k<<<(NL * 128 + 255) / 256, 256, 0, stream>>>(ndb, eqb, nsb, kvb, qb2);

    // ---- CSR build ----
    const int nbG = (NN + 255) / 256, nbE = (NEL + 255) / 256;
    zero_k<<<nbG, 256, 0, stream>>>((float*)gcnt, NN);
    hist_k<<<(NE + 255) / 256, 256, 0, stream>>>(g_dst, gcnt, NE);
    scanA_k<<<nbG, 256, 0, stream>>>(gcnt, goff, bsum, NN);
    scanB_k<<<1, 1024, 0, stream>>>(bsum, nbG);
    scanC_k<<<nbG, 256, 0, stream>>>(bsum, goff, gcur, NN);
    scatter_k<<<(NE + 255) / 256, 256, 0, stream>>>(g_dst, gcur, gord, NE);
    zero_k<<<nbE, 256, 0, stream>>>((float*)ecnt, NEL);
    hist_k<<<(NLG + 255) / 256, 256, 0, stream>>>(lg_dst, ecnt, NLG);
    scanA_k<<<nbE, 256, 0, stream>>>(ecnt, eoff, bsum, NEL);
    scanB_k<<<1, 1024, 0, stream>>>(bsum, nbE);
    scanC_k<<<nbE, 256, 0, stream>>>(bsum, eoff, ecur, NEL);
    scatter_k<<<(NLG + 255) / 256, 256, 0, stream>>>(lg_dst, ecur, eord, NLG);
    pack_k<<<(NLG + 255) / 256, 256, 0, stream>>>(gord, g_src, eord, lg_src, npack, esrc);

    const int ndD = NN * DD;
    const int elD = NEL * ED;
    castcopy_k<<<(ndD + 255) / 256, 256, 0, stream>>>(x_in, xbuf, xb, ndD);
    init_lg_k<<<(NE * ED + 255) / 256, 256, 0, stream>>>(rel, edge_feat, lgb);
    gather64_k<<<(elD + 255) / 256, 256, 0, stream>>>(lgb, local_index, el, elb);

    for (int i = 0; i < NL; ++i) {
        size_t oD2 = (size_t)i * DD * DD, oE2 = (size_t)i * ED * ED;

        // ---- node attention (reads lgb BEFORE this layer's edge update) ----
        run_gemm(stream, xb, WqkvT + (size_t)i * QKVW * DD, qkvb + (size_t)i * QKVW,
                 nullptr, nullptr, qkv, NN, DD, QKVW, 0, false);
        node_attn_csr_k<<<NN / 4, 256, 0, stream>>>(qkv, lgb, goff, npack, ob);
        run_gemm(stream, ob, WoT + oD2, bo + (size_t)i * DD, xbuf, t0, nullptr, NN, DD, DD, 0, true);
        ln_k<<<(NN + 3) / 4, 256, 0, stream>>>(t0, ln1g + (size_t)i * DD, ln1b + (size_t)i * DD,
                                               t0, DD, NN, hb, nullptr, nullptr);

        // ---- edge branch (fused split-K GEMMs) ----
        run_gemm2(stream, elb, xb, dst_ids, KVET + (size_t)i * 128 * 576,
                  kvb + (size_t)i * 128, keve, NEL, 576, 128, 64, true);
        run_gemm2(stream, elb, xb, src_ids, QET + (size_t)i * 64 * 576,
                  qb2 + (size_t)i * 64, qeb, NEL, 576, 64, 64, true);
        lg_attn_csr_k<<<NEL / 4, 256, 0, stream>>>(qeb, keve, eoff, esrc, e1b);
        run_gemm(stream, e1b, EoT + oE2, eob + (size_t)i * ED, el, t2, nullptr, NEL, ED, ED, 0, true);
        ln_k<<<(NEL + 3) / 4, 256, 0, stream>>>(t2, eln1g + (size_t)i * ED, eln1b + (size_t)i * ED,
                                                t2, ED, NEL, heb, nullptr, nullptr);
        run_gemm(stream, heb, G1T + (size_t)i * ED * 4 * ED, g1b + (size_t)i * 4 * ED,
                 nullptr, nullptr, fgb, NEL, ED, 4 * ED, 1, false);
        run_gemm(stream, fgb, G2T + (size_t)i * 4 * ED * ED, g2b + (size_t)i * ED,
                 t2, t3, nullptr, NEL, 4 * ED, ED, 0, true);
        ln_k<<<(NEL + 3) / 4, 256, 0, stream>>>(t3, eln2g + (size_t)i * ED, eln2b + (size_t)i * ED,
                                                el, ED, NEL, elb, lgb, local_index);

        // ---- node FFN ----
        run_gemm(stream, hb, F1T + (size_t)i * DD * 4 * DD, f1b + (size_t)i * 4 * DD,
                 nullptr, nullptr, fgb, NN, DD, 4 * DD, 1, false);
        run_gemm(stream, fgb, F2T + (size_t)i * 4 * DD * DD, f2b_ + (size_t)i * DD,
                 t0, xbuf, nullptr, NN, 2048, DD, 0, true);
        ln_k<<<(NN + 3) / 4, 256, 0, stream>>>(xbuf, ln2g + (size_t)i * DD, ln2b + (size_t)i * DD,
                                               xbuf, DD, NN, xb, nullptr, nullptr);
    }
    // outputs already in d_out
}

// Round 10
// 1806.321 us; speedup vs baseline: 1.2353x; 1.2039x over previous
//
#include <hip/hip_runtime.h>
#include <math.h>

#define NN   10000      // nodes
#define DD   512        // node dim
#define NH   8          // node heads (DK=64)
#define NE   120000     // edges (global)
#define NEL  60000      // local edges
#define NLG  600000     // line-graph edges
#define ED   64         // edge dim (EH=8, EDK=8)
#define NEH  8
#define NL   4          // layers
#define QKVW 1536       // fused q|k|v row width

typedef __attribute__((ext_vector_type(8))) short bf16x8;
typedef __attribute__((ext_vector_type(8))) unsigned short u16x8;
typedef __attribute__((ext_vector_type(4))) float f32x4;

__device__ __forceinline__ unsigned short f2b(float f) {
    union { float f; unsigned u; } c; c.f = f;
    unsigned u = c.u;
    unsigned r = u + 0x7FFFu + ((u >> 16) & 1u);
    return (unsigned short)(r >> 16);
}
__device__ __forceinline__ float b2f(unsigned short b) {
    union { unsigned u; float f; } c; c.u = ((unsigned)b) << 16;
    return c.f;
}

// async global->LDS, 16B per lane; LDS dest is wave-uniform base + lane*16 (HW)
__device__ __forceinline__ void gl16(const unsigned short* g, unsigned short* l) {
    __builtin_amdgcn_global_load_lds(
        (const __attribute__((address_space(1))) unsigned int*)g,
        (__attribute__((address_space(3))) unsigned int*)l, 16, 0, 0);
}

// ---------------- elementwise helpers ----------------
static __global__ __launch_bounds__(256)
void zero_k(float* __restrict__ p, int n) {
    int i = blockIdx.x * 256 + threadIdx.x;
    if (i < n) p[i] = 0.0f;
}

static __global__ __launch_bounds__(256)
void castcopy_k(const float* __restrict__ s, float* __restrict__ d,
                unsigned short* __restrict__ db, int n) {
    int i = blockIdx.x * 256 + threadIdx.x;
    if (i < n) { float v = s[i]; if (d) d[i] = v; db[i] = f2b(v); }
}

static __global__ __launch_bounds__(256)
void init_lg_k(const float* __restrict__ rel, const int* __restrict__ ef,
               unsigned short* __restrict__ lgb) {
    int i = blockIdx.x * 256 + threadIdx.x;
    if (i >= NE * ED) return;
    int e = i >> 6, c = i & 63;
    lgb[i] = f2b(rel[ef[e] * ED + c]);
}

static __global__ __launch_bounds__(256)
void gather64_k(const unsigned short* __restrict__ lgb, const int* __restrict__ idx,
                float* __restrict__ el, unsigned short* __restrict__ elb) {
    int i = blockIdx.x * 256 + threadIdx.x;
    if (i >= NEL * ED) return;
    int r = i >> 6;
    unsigned short b = lgb[(long)idx[r] * ED + (i & 63)];
    el[i] = b2f(b); elb[i] = b;
}

// ---------------- LDS-tiled transpose+cast ----------------
static __global__ __launch_bounds__(256)
void ttrans_k(const float* __restrict__ in, unsigned short* __restrict__ out,
              int K, int N, long lstride, int rowStride, int rowOff, int colOff) {
    __shared__ float sm[32][33];
    const int l = blockIdx.z;
    const int kt = blockIdx.x * 32, nt = blockIdx.y * 32;
    const int tx = threadIdx.x & 31, ty = threadIdx.x >> 5;
    const float* ip = in + (size_t)l * K * N;
    #pragma unroll
    for (int r = 0; r < 4; ++r)
        sm[ty + 8 * r][tx] = ip[(size_t)(kt + ty + 8 * r) * N + nt + tx];
    __syncthreads();
    unsigned short* op = out + (size_t)l * lstride;
    #pragma unroll
    for (int r = 0; r < 4; ++r) {
        int n = nt + ty + 8 * r;
        op[(size_t)(rowOff + n) * rowStride + colOff + kt + tx] = f2b(sm[tx][ty + 8 * r]);
    }
}

static __global__ __launch_bounds__(256)
void build_qkvb_k(const float* __restrict__ bq, float* __restrict__ out) {
    int i = blockIdx.x * 256 + threadIdx.x;
    if (i >= NL * QKVW) return;
    int l = i / QKVW, c = i - l * QKVW;
    out[i] = (c < 512) ? bq[l * 512 + c] : 0.0f;
}

static __global__ __launch_bounds__(256)
void ebias_k(const float* __restrict__ ndb, const float* __restrict__ eqb,
             const float* __restrict__ nsb, float* __restrict__ kvb,
             float* __restrict__ qb2) {
    int i = blockIdx.x * 256 + threadIdx.x;
    if (i < NL * 128) kvb[i] = ndb[(i >> 7) * 64 + (i & 63)];
    if (i < NL * 64)  qb2[i] = eqb[i] + nsb[i];
}

// ---------------- CSR build ----------------
static __global__ __launch_bounds__(256)
void hist_k(const int* __restrict__ dst, int* __restrict__ cnt, int n) {
    int i = blockIdx.x * 256 + threadIdx.x;
    if (i < n) atomicAdd(&cnt[dst[i]], 1);
}

static __global__ __launch_bounds__(256)
void scanA_k(const int* __restrict__ cnt, int* __restrict__ off,
             int* __restrict__ bsum, int n) {
    __shared__ int sm[256];
    const int t = threadIdx.x;
    const int i = blockIdx.x * 256 + t;
    int v = (i < n) ? cnt[i] : 0;
    sm[t] = v; __syncthreads();
    int x = v;
    #pragma unroll
    for (int d = 1; d < 256; d <<= 1) {
        int y = (t >= d) ? sm[t - d] : 0;
        __syncthreads();
        x += y; sm[t] = x; __syncthreads();
    }
    if (i < n) off[i] = x - v;
    if (t == 255) bsum[blockIdx.x] = x;
}

static __global__ __launch_bounds__(1024)
void scanB_k(int* __restrict__ bsum, int nb) {
    __shared__ int sm[1024];
    const int t = threadIdx.x;
    int v = (t < nb) ? bsum[t] : 0;
    sm[t] = v; __syncthreads();
    int x = v;
    #pragma unroll
    for (int d = 1; d < 1024; d <<= 1) {
        int y = (t >= d) ? sm[t - d] : 0;
        __syncthreads();
        x += y; sm[t] = x; __syncthreads();
    }
    if (t < nb) bsum[t] = x - v;
}

static __global__ __launch_bounds__(256)
void scanC_k(const int* __restrict__ bsum, int* __restrict__ off,
             int* __restrict__ cur, int n) {
    int i = blockIdx.x * 256 + threadIdx.x;
    if (i < n) { int o = off[i] + bsum[blockIdx.x]; off[i] = o; cur[i] = o; }
}

static __global__ __launch_bounds__(256)
void scatter_k(const int* __restrict__ dst, int* __restrict__ cur,
               int* __restrict__ ord, int n) {
    int i = blockIdx.x * 256 + threadIdx.x;
    if (i < n) { int p = atomicAdd(&cur[dst[i]], 1); ord[p] = i; }
}

static __global__ __launch_bounds__(256)
void pack_k(const int* __restrict__ gord, const int* __restrict__ gsrc,
            const int* __restrict__ eord, const int* __restrict__ lsrc,
            int2* __restrict__ npack, int* __restrict__ esrc) {
    int i = blockIdx.x * 256 + threadIdx.x;
    if (i < NE) { int e = gord[i]; npack[i] = make_int2(e, gsrc[e]); }
    if (i < NLG) esrc[i] = lsrc[eord[i]];
}

// ---------------- bf16 MFMA GEMM: BMxBN tile, BK=32, single-buf LDS --------
// 64x64 tile: 8KB LDS -> 8 blocks/CU; small-N grids get 2x blocks (TLP).
// If A2==null: C = A[M,K] @ Bt[Nc,K]^T; else A-row r = [A[r][0:K1] | A2[idx2[r]][:]]
// addC (fp32) or addCb (bf16) residual; output C fp32 or Cb bf16.
#define FSWZ(r) (((r) & 3) ^ (((r) >> 2) & 3))
template<int BM, int BN>
static __global__ __launch_bounds__(256)
void gemm_bf16_k(const unsigned short* __restrict__ A,
                 const unsigned short* __restrict__ A2, const int* __restrict__ idx2,
                 const unsigned short* __restrict__ Bt, const float* __restrict__ bias,
                 const float* __restrict__ addC, const unsigned short* __restrict__ addCb,
                 float* __restrict__ C, unsigned short* __restrict__ Cb,
                 int M, int K, int Nc, int doRelu, int K1)
{
    constexpr int MI = BM / 32, NI = BN / 32;   // frags per wave
    constexpr int AC = BM / 64, BC = BN / 64;   // gl16 per wave
    __shared__ unsigned short Asl[BM * 32];
    __shared__ unsigned short Bsl[BN * 32];
    const int tid  = threadIdx.x;
    const int lane = tid & 63;
    const int wave = tid >> 6;
    const int wr = (wave >> 1) * (BM / 2);
    const int wc = (wave & 1) * (BN / 2);

    // XCD-aware bijective block swizzle (m204)
    const int nwg = gridDim.x * gridDim.y;
    const int hw = blockIdx.y * gridDim.x + blockIdx.x;
    const int q8 = nwg >> 3, r8 = nwg & 7;
    const int xcd = hw & 7, rest = hw >> 3;
    const int logical = (xcd < r8 ? xcd * (q8 + 1) : r8 * (q8 + 1) + (xcd - r8) * q8) + rest;
    const int bm = (logical / gridDim.x) * BM;
    const int bn = (logical % gridDim.x) * BN;

    // staging geometry: lane -> row rl (16 rows per gl16), slot sl
    const int rl = lane >> 2;                 // 0..15
    const int sl = lane & 3;
    int ga[AC]; long ia[AC]; bool av[AC]; int acw[AC];
    #pragma unroll
    for (int c = 0; c < AC; ++c) {
        int ar = wave * (BM / 4) + c * 16 + rl;
        ga[c] = bm + ar;
        av[c] = ga[c] < M;
        ia[c] = (A2 && av[c]) ? (long)idx2[ga[c]] : 0;
        acw[c] = (sl ^ FSWZ(ar)) * 8;
    }
    int gb[BC]; int bcw[BC];
    #pragma unroll
    for (int c = 0; c < BC; ++c) {
        int br = wave * (BN / 4) + c * 16 + rl;
        gb[c] = bn + br;
        bcw[c] = (sl ^ FSWZ(br)) * 8;
    }

    auto stage = [&](int k0) {
        #pragma unroll
        for (int c = 0; c < AC; ++c) {
            const unsigned short* s;
            if (!A2)            s = A  + (long)ga[c] * K  + k0 + acw[c];
            else if (k0 < K1)   s = A  + (long)ga[c] * K1 + k0 + acw[c];
            else                s = A2 + ia[c] * DD + (k0 - K1) + acw[c];
            if (av[c]) gl16(s, Asl + (wave * (BM / 4) + c * 16) * 32);
        }
        #pragma unroll
        for (int c = 0; c < BC; ++c)
            gl16(Bt + (long)gb[c] * K + k0 + bcw[c],
                 Bsl + (wave * (BN / 4) + c * 16) * 32);
    };

    f32x4 acc[MI][NI] = {};
    const int rbase = lane & 15;
    const int ks = lane >> 4;

    for (int k0 = 0; k0 < K; k0 += 32) {
        stage(k0);
        __syncthreads();                      // staged tile landed (vmcnt drained)
        bf16x8 af[MI]; bf16x8 bfr[NI];
        #pragma unroll
        for (int mi = 0; mi < MI; ++mi) {
            int r = wr + mi * 16 + rbase;
            int s = ks ^ FSWZ(r);
            af[mi] = *reinterpret_cast<const bf16x8*>(Asl + r * 32 + s * 8);
        }
        #pragma unroll
        for (int ni = 0; ni < NI; ++ni) {
            int r = wc + ni * 16 + rbase;
            int s = ks ^ FSWZ(r);
            bfr[ni] = *reinterpret_cast<const bf16x8*>(Bsl + r * 32 + s * 8);
        }
        #pragma unroll
        for (int mi = 0; mi < MI; ++mi)
            #pragma unroll
            for (int ni = 0; ni < NI; ++ni)
                acc[mi][ni] = __builtin_amdgcn_mfma_f32_16x16x32_bf16(
                    af[mi], bfr[ni], acc[mi][ni], 0, 0, 0);
        __syncthreads();                      // ds_reads done before re-stage
    }

    const int colBase = bn + wc + rbase;
    const int rowBase = bm + wr + ks * 4;
    #pragma unroll
    for (int mi = 0; mi < MI; ++mi) {
        #pragma unroll
        for (int j = 0; j < 4; ++j) {
            int r = rowBase + mi * 16 + j;
            if (r >= M) continue;
            long ro = (long)r * Nc;
            #pragma unroll
            for (int ni = 0; ni < NI; ++ni) {
                int cc = colBase + ni * 16;
                if (cc >= Nc) continue;
                float v = acc[mi][ni][j];
                if (bias)  v += bias[cc];
                if (doRelu) v = fmaxf(v, 0.0f);
                if (addC)  v += addC[ro + cc];
                else if (addCb) v += b2f(addCb[ro + cc]);
                if (Cb) Cb[ro + cc] = f2b(v);
                else    C[ro + cc] = v;
            }
        }
    }
}
#undef FSWZ

// ---------------- LayerNorm (wave per row, 4 rows/block) ----------------
static __global__ __launch_bounds__(256)
void ln_k(const float* __restrict__ in, const float* __restrict__ g,
          const float* __restrict__ b, float* __restrict__ out, int Dw, int nrows,
          unsigned short* __restrict__ outb,
          unsigned short* __restrict__ out2b, const int* __restrict__ idx2)
{
    const int row = blockIdx.x * 4 + (threadIdx.x >> 6);
    if (row >= nrows) return;
    const int lane = threadIdx.x & 63;
    const int per = Dw >> 6;
    float v[8];
    const float* rp = in + (long)row * Dw;
    float s = 0.f;
    for (int i = 0; i < per; ++i) { v[i] = rp[i * 64 + lane]; s += v[i]; }
    #pragma unroll
    for (int off = 32; off; off >>= 1) s += __shfl_xor(s, off, 64);
    const float mu = s / (float)Dw;
    float var = 0.f;
    for (int i = 0; i < per; ++i) { float d = v[i] - mu; var += d * d; }
    #pragma unroll
    for (int off = 32; off; off >>= 1) var += __shfl_xor(var, off, 64);
    const float rstd = rsqrtf(var / (float)Dw + 1e-5f);
    for (int i = 0; i < per; ++i) {
        int c = i * 64 + lane;
        float o = (v[i] - mu) * rstd * g[c] + b[c];
        if (out)   out[(long)row * Dw + c] = o;
        if (outb)  outb[(long)row * Dw + c] = f2b(o);
        if (out2b) out2b[(long)idx2[row] * Dw + c] = f2b(o);
    }
}

// ---------------- node attention, CSR, 2-way unrolled ----------------
static __global__ __launch_bounds__(256)
void node_attn_csr_k(const unsigned short* __restrict__ qkv,
                     const unsigned short* __restrict__ lgb,
                     const int* __restrict__ goff, const int2* __restrict__ npack,
                     unsigned short* __restrict__ ob)
{
    int node = blockIdx.x * 4 + (threadIdx.x >> 6);
    if (node >= NN) return;
    const int lane = threadIdx.x & 63;
    float qv[8];
    {
        u16x8 q8 = *reinterpret_cast<const u16x8*>(qkv + (long)node * QKVW + lane * 8);
        #pragma unroll
        for (int i = 0; i < 8; ++i) qv[i] = b2f(q8[i]);
    }
    float wva[8] = {0.f, 0.f, 0.f, 0.f, 0.f, 0.f, 0.f, 0.f};
    float zac = 0.f;
    int j = goff[node];
    const int hi = (node + 1 < NN) ? goff[node + 1] : NE;
    const int eoffl = (lane & 7) * 8;

    for (; j + 2 <= hi; j += 2) {
        int2 pa = npack[j], pb = npack[j + 1];
        u16x8 kA = *reinterpret_cast<const u16x8*>(qkv + (long)pa.y * QKVW + 512 + lane * 8);
        u16x8 vA = *reinterpret_cast<const u16x8*>(qkv + (long)pa.y * QKVW + 1024 + lane * 8);
        u16x8 eA = *reinterpret_cast<const u16x8*>(lgb + (long)pa.x * ED + eoffl);
        u16x8 kB = *reinterpret_cast<const u16x8*>(qkv + (long)pb.y * QKVW + 512 + lane * 8);
        u16x8 vB = *reinterpret_cast<const u16x8*>(qkv + (long)pb.y * QKVW + 1024 + lane * 8);
        u16x8 eB = *reinterpret_cast<const u16x8*>(lgb + (long)pb.x * ED + eoffl);
        float edA[8], vvA[8], edB[8], vvB[8];
        float pA = 0.f, pB = 0.f;
        #pragma unroll
        for (int i = 0; i < 8; ++i) {
            edA[i] = b2f(eA[i]); vvA[i] = b2f(vA[i]);
            pA = fmaf(b2f(kA[i]) + edA[i], qv[i], pA);
            edB[i] = b2f(eB[i]); vvB[i] = b2f(vB[i]);
            pB = fmaf(b2f(kB[i]) + edB[i], qv[i], pB);
        }
        pA += __shfl_xor(pA, 1, 64); pA += __shfl_xor(pA, 2, 64); pA += __shfl_xor(pA, 4, 64);
        pB += __shfl_xor(pB, 1, 64); pB += __shfl_xor(pB, 2, 64); pB += __shfl_xor(pB, 4, 64);
        float wA = expf(fminf(fmaxf(pA * 0.125f, -10.0f), 10.0f));
        float wB = expf(fminf(fmaxf(pB * 0.125f, -10.0f), 10.0f));
        #pragma unroll
        for (int i = 0; i < 8; ++i) {
            wva[i] = fmaf(wA, vvA[i] + edA[i], wva[i]);
            wva[i] = fmaf(wB, vvB[i] + edB[i], wva[i]);
        }
        zac += wA + wB;
    }
    for (; j < hi; ++j) {
        int2 pa = npack[j];
        u16x8 kA = *reinterpret_cast<const u16x8*>(qkv + (long)pa.y * QKVW + 512 + lane * 8);
        u16x8 vA = *reinterpret_cast<const u16x8*>(qkv + (long)pa.y * QKVW + 1024 + lane * 8);
        u16x8 eA = *reinterpret_cast<const u16x8*>(lgb + (long)pa.x * ED + eoffl);
        float edA[8], vvA[8];
        float pA = 0.f;
        #pragma unroll
        for (int i = 0; i < 8; ++i) {
            edA[i] = b2f(eA[i]); vvA[i] = b2f(vA[i]);
            pA = fmaf(b2f(kA[i]) + edA[i], qv[i], pA);
        }
        pA += __shfl_xor(pA, 1, 64); pA += __shfl_xor(pA, 2, 64); pA += __shfl_xor(pA, 4, 64);
        float wA = expf(fminf(fmaxf(pA * 0.125f, -10.0f), 10.0f));
        #pragma unroll
        for (int i = 0; i < 8; ++i) wva[i] = fmaf(wA, vvA[i] + edA[i], wva[i]);
        zac += wA;
    }
    const float inv = 1.0f / fmaxf(zac, 1e-9f);
    u16x8 o8;
    #pragma unroll
    for (int i = 0; i < 8; ++i) o8[i] = f2b(wva[i] * inv);
    *reinterpret_cast<u16x8*>(ob + (long)node * DD + lane * 8) = o8;
}

// ---------------- line-graph attention, CSR, 4-way unrolled ----------------
static __global__ __launch_bounds__(256)
void lg_attn_csr_k(const unsigned short* __restrict__ qeb,
                   const unsigned short* __restrict__ keve,
                   const int* __restrict__ eoff, const int* __restrict__ esrc,
                   unsigned short* __restrict__ oeb)
{
    int d = blockIdx.x * 4 + (threadIdx.x >> 6);
    if (d >= NEL) return;
    const int lane = threadIdx.x & 63;
    const float qv = b2f(qeb[(long)d * ED + lane]);
    float oa = 0.f, zac = 0.f;
    int j = eoff[d];
    const int hi = (d + 1 < NEL) ? eoff[d + 1] : NLG;
    for (; j + 4 <= hi; j += 4) {
        int ss[4]; float kk[4], vv[4];
        #pragma unroll
        for (int u = 0; u < 4; ++u) ss[u] = esrc[j + u];
        #pragma unroll
        for (int u = 0; u < 4; ++u) {
            kk[u] = b2f(keve[(long)ss[u] * 128 + lane]);
            vv[u] = b2f(keve[(long)ss[u] * 128 + 64 + lane]);
        }
        #pragma unroll
        for (int u = 0; u < 4; ++u) {
            float p = kk[u] * qv;
            p += __shfl_xor(p, 1, 64); p += __shfl_xor(p, 2, 64); p += __shfl_xor(p, 4, 64);
            float w = expf(fminf(fmaxf(p * 0.35355339059327373f, -10.0f), 10.0f));
            oa = fmaf(w, vv[u], oa);
            zac += w;
        }
    }
    for (; j < hi; ++j) {
        int s = esrc[j];
        float kv = b2f(keve[(long)s * 128 + lane]);
        float vv = b2f(keve[(long)s * 128 + 64 + lane]);
        float p = kv * qv;
        p += __shfl_xor(p, 1, 64); p += __shfl_xor(p, 2, 64); p += __shfl_xor(p, 4, 64);
        float w = expf(fminf(fmaxf(p * 0.35355339059327373f, -10.0f), 10.0f));
        oa = fmaf(w, vv, oa);
        zac += w;
    }
    oeb[(long)d * ED + lane] = f2b(oa / fmaxf(zac, 1e-9f));
}

// ---------------- host ----------------
static inline void run_gemm(hipStream_t st, const unsigned short* A,
                            const unsigned short* Bt, const float* bias,
                            const float* addC, const unsigned short* addCb,
                            float* C, unsigned short* Cb,
                            int M, int K, int Nc, int relu)
{
    dim3 g((Nc + 63) / 64, (M + 63) / 64);
    gemm_bf16_k<64, 64><<<g, 256, 0, st>>>(A, nullptr, nullptr, Bt, bias, addC, addCb,
                                           C, Cb, M, K, Nc, relu, 0);
}
static inline void run_gemm2(hipStream_t st, const unsigned short* A1,
                             const unsigned short* A2, const int* idx2,
                             const unsigned short* Bt, const float* bias,
                             unsigned short* Cb, int M, int K, int Nc, int K1)
{
    dim3 g((Nc + 63) / 64, (M + 63) / 64);
    gemm_bf16_k<64, 64><<<g, 256, 0, st>>>(A1, A2, idx2, Bt, bias, nullptr, nullptr,
                                           nullptr, Cb, M, K, Nc, 0, K1);
}

extern "C" void kernel_launch(void* const* d_in, const int* in_sizes, int n_in,
                              void* d_out, int out_size, void* d_ws, size_t ws_size,
                              hipStream_t stream)
{
    const float* x_in  = (const float*)d_in[0];
    const float* rel   = (const float*)d_in[1];
    const float* Wq    = (const float*)d_in[2];
    const float* bq    = (const float*)d_in[3];
    const float* Wk    = (const float*)d_in[4];
    const float* Wv    = (const float*)d_in[5];
    const float* Wo    = (const float*)d_in[6];
    const float* bo    = (const float*)d_in[7];
    const float* ln1g  = (const float*)d_in[8];
    const float* ln1b  = (const float*)d_in[9];
    const float* F1    = (const float*)d_in[10];
    const float* f1b   = (const float*)d_in[11];
    const float* F2    = (const float*)d_in[12];
    const float* f2b_  = (const float*)d_in[13];
    const float* ln2g  = (const float*)d_in[14];
    const float* ln2b  = (const float*)d_in[15];
    const float* Eq    = (const float*)d_in[16];
    const float* eqb   = (const float*)d_in[17];
    const float* Ek    = (const float*)d_in[18];
    const float* Ev    = (const float*)d_in[19];
    const float* Eo    = (const float*)d_in[20];
    const float* eob   = (const float*)d_in[21];
    const float* Ns    = (const float*)d_in[22];
    const float* nsb   = (const float*)d_in[23];
    const float* Nd    = (const float*)d_in[24];
    const float* ndb   = (const float*)d_in[25];
    const float* eln1g = (const float*)d_in[26];
    const float* eln1b = (const float*)d_in[27];
    const float* G1    = (const float*)d_in[28];
    const float* g1b   = (const float*)d_in[29];
    const float* G2    = (const float*)d_in[30];
    const float* g2b   = (const float*)d_in[31];
    const float* eln2g = (const float*)d_in[32];
    const float* eln2b = (const float*)d_in[33];
    const int* edge_feat   = (const int*)d_in[34];
    const int* local_index = (const int*)d_in[35];
    const int* src_ids     = (const int*)d_in[36];
    const int* dst_ids     = (const int*)d_in[37];
    const int* g_src       = (const int*)d_in[38];
    const int* g_dst       = (const int*)d_in[39];
    const int* lg_src      = (const int*)d_in[40];
    const int* lg_dst      = (const int*)d_in[41];

    // outputs live in d_out
    float* xbuf = (float*)d_out;                   // (NN, DD)
    float* el   = xbuf + (size_t)NN * DD;          // (NEL, ED)

    // ---- workspace layout (~214 MB) ----
    float* W = (float*)d_ws;
    size_t off = 0;
    auto alloc = [&](size_t n) { float* p = W + off; off += (n + 63) & ~(size_t)63; return p; };
    float* t0  = alloc((size_t)NN * DD);
    float* t2  = alloc((size_t)NEL * ED);
    float* t3  = alloc((size_t)NEL * ED);
    float* qkvb = alloc((size_t)NL * QKVW);
    float* kvb  = alloc((size_t)NL * 128);
    float* qb2  = alloc((size_t)NL * ED);

    unsigned short* bp = (unsigned short*)(W + off);
    size_t boff = 0;
    auto balloc = [&](size_t n) { unsigned short* p = bp + boff; boff += (n + 63) & ~(size_t)63; return p; };
    unsigned short* lgb = balloc((size_t)NE * ED);
    unsigned short* xb  = balloc((size_t)NN * DD);
    unsigned short* qkv = balloc((size_t)NN * QKVW);
    unsigned short* elb = balloc((size_t)NEL * ED);
    unsigned short* e1b = balloc((size_t)NEL * ED);
    unsigned short* heb = balloc((size_t)NEL * ED);
    unsigned short* qeb = balloc((size_t)NEL * ED);
    unsigned short* fgb = balloc((size_t)NN * 4 * DD);
    unsigned short* hb   = qkv;
    unsigned short* keve = qkv + (size_t)NN * DD;
    unsigned short* ob   = fgb;
    unsigned short* WqkvT = balloc((size_t)NL * QKVW * DD);
    unsigned short* WoT  = balloc((size_t)NL * DD * DD);
    unsigned short* F1T  = balloc((size_t)NL * DD * 4 * DD);
    unsigned short* F2T  = balloc((size_t)NL * 4 * DD * DD);
    unsigned short* KVET = balloc((size_t)NL * 128 * 576);
    unsigned short* QET  = balloc((size_t)NL * 64 * 576);
    unsigned short* EoT  = balloc((size_t)NL * ED * ED);
    unsigned short* G1T  = balloc((size_t)NL * ED * 4 * ED);
    unsigned short* G2T  = balloc((size_t)NL * 4 * ED * ED);
    int* ip = (int*)(bp + ((boff + 63) & ~(size_t)63));
    size_t ioff = 0;
    auto ialloc = [&](size_t n) { int* p = ip + ioff; ioff += (n + 63) & ~(size_t)63; return p; };
    int* gcnt = ialloc(NN);
    int* goff = ialloc(NN);
    int* gcur = ialloc(NN);
    int* gord = ialloc(NE);
    int2* npack = (int2*)ialloc(2 * (size_t)NE);
    int* ecnt = ialloc(NEL);
    int* eoff = ialloc(NEL);
    int* ecur = ialloc(NEL);
    int* eord = ialloc(NLG);
    int* esrc = ialloc(NLG);
    int* bsum = ialloc(1024);

    // ---- weight prep ----
    auto tt = [&](const float* src, unsigned short* dst, int K, int N,
                  long lstride, int rowStride, int rowOff, int colOff) {
        dim3 g(K / 32, N / 32, NL);
        ttrans_k<<<g, 256, 0, stream>>>(src, dst, K, N, lstride, rowStride, rowOff, colOff);
    };
    tt(Wq, WqkvT, 512, 512, (long)QKVW * DD, DD, 0, 0);
    tt(Wk, WqkvT, 512, 512, (long)QKVW * DD, DD, 512, 0);
    tt(Wv, WqkvT, 512, 512, (long)QKVW * DD, DD, 1024, 0);
    tt(Wo, WoT, 512, 512, (long)DD * DD, DD, 0, 0);
    tt(F1, F1T, 512, 2048, (long)DD * 4 * DD, DD, 0, 0);
    tt(F2, F2T, 2048, 512, (long)4 * DD * DD, 4 * DD, 0, 0);
    tt(Ek, KVET, 64, 64, (long)128 * 576, 576, 0, 0);
    tt(Nd, KVET, 512, 64, (long)128 * 576, 576, 0, 64);
    tt(Ev, KVET, 64, 64, (long)128 * 576, 576, 64, 0);
    tt(Nd, KVET, 512, 64, (long)128 * 576, 576, 64, 64);
    tt(Eq, QET, 64, 64, (long)64 * 576, 576, 0, 0);
    tt(Ns, QET, 512, 64, (long)64 * 576, 576, 0, 64);
    tt(Eo, EoT, 64, 64, (long)ED * ED, ED, 0, 0);
    tt(G1, G1T, 64, 256, (long)ED * 4 * ED, ED, 0, 0);
    tt(G2, G2T, 256, 64, (long)4 * ED * ED, 4 * ED, 0, 0);
    build_qkvb_k<<<(NL * QKVW + 255) / 256, 256, 0, stream>>>(bq, qkvb);
    ebias_k<<<(NL * 128 + 255) / 256, 256, 0, stream>>>(ndb, eqb, nsb, kvb, qb2);

    // ---- CSR build ----
    const int nbG = (NN + 255) / 256, nbE = (NEL + 255) / 256;
    zero_k<<<nbG, 256, 0, stream>>>((float*)gcnt, NN);
    hist_k<<<(NE + 255) / 256, 256, 0, stream>>>(g_dst, gcnt, NE);
    scanA_k<<<nbG, 256, 0, stream>>>(gcnt, goff, bsum, NN);
    scanB_k<<<1, 1024, 0, stream>>>(bsum, nbG);
    scanC_k<<<nbG, 256, 0, stream>>>(bsum, goff, gcur, NN);
    scatter_k<<<(NE + 255) / 256, 256, 0, stream>>>(g_dst, gcur, gord, NE);
    zero_k<<<nbE, 256, 0, stream>>>((float*)ecnt, NEL);
    hist_k<<<(NLG + 255) / 256, 256, 0, stream>>>(lg_dst, ecnt, NLG);
    scanA_k<<<nbE, 256, 0, stream>>>(ecnt, eoff, bsum, NEL);
    scanB_k<<<1, 1024, 0, stream>>>(bsum, nbE);
    scanC_k<<<nbE, 256, 0, stream>>>(bsum, eoff, ecur, NEL);
    scatter_k<<<(NLG + 255) / 256, 256, 0, stream>>>(lg_dst, ecur, eord, NLG);
    pack_k<<<(NLG + 255) / 256, 256, 0, stream>>>(gord, g_src, eord, lg_src, npack, esrc);

    const int ndD = NN * DD;
    const int elD = NEL * ED;
    castcopy_k<<<(ndD + 255) / 256, 256, 0, stream>>>(x_in, xbuf, xb, ndD);
    init_lg_k<<<(NE * ED + 255) / 256, 256, 0, stream>>>(rel, edge_feat, lgb);
    gather64_k<<<(elD + 255) / 256, 256, 0, stream>>>(lgb, local_index, el, elb);

    for (int i = 0; i < NL; ++i) {
        size_t oD2 = (size_t)i * DD * DD, oE2 = (size_t)i * ED * ED;

        // ---- node attention (reads lgb BEFORE this layer's edge update) ----
        run_gemm(stream, xb, WqkvT + (size_t)i * QKVW * DD, qkvb + (size_t)i * QKVW,
                 nullptr, nullptr, nullptr, qkv, NN, DD, QKVW, 0);
        node_attn_csr_k<<<NN / 4, 256, 0, stream>>>(qkv, lgb, goff, npack, ob);
        // t0 = x_in + o @ Wo + bo  (bf16 residual xb)
        run_gemm(stream, ob, WoT + oD2, bo + (size_t)i * DD, nullptr, xb, t0, nullptr, NN, DD, DD, 0);
        ln_k<<<(NN + 3) / 4, 256, 0, stream>>>(t0, ln1g + (size_t)i * DD, ln1b + (size_t)i * DD,
                                               nullptr, DD, NN, hb, nullptr, nullptr);

        // ---- edge branch (fused split-K GEMMs) ----
        run_gemm2(stream, elb, xb, dst_ids, KVET + (size_t)i * 128 * 576,
                  kvb + (size_t)i * 128, keve, NEL, 576, 128, 64);
        run_gemm2(stream, elb, xb, src_ids, QET + (size_t)i * 64 * 576,
                  qb2 + (size_t)i * 64, qeb, NEL, 576, 64, 64);
        lg_attn_csr_k<<<NEL / 4, 256, 0, stream>>>(qeb, keve, eoff, esrc, e1b);
        // t2 = el + oe @ Eo + eob  (bf16 residual elb)
        run_gemm(stream, e1b, EoT + oE2, eob + (size_t)i * ED, nullptr, elb, t2, nullptr, NEL, ED, ED, 0);
        ln_k<<<(NEL + 3) / 4, 256, 0, stream>>>(t2, eln1g + (size_t)i * ED, eln1b + (size_t)i * ED,
                                                nullptr, ED, NEL, heb, nullptr, nullptr);
        run_gemm(stream, heb, G1T + (size_t)i * ED * 4 * ED, g1b + (size_t)i * 4 * ED,
                 nullptr, nullptr, nullptr, fgb, NEL, ED, 4 * ED, 1);
        run_gemm(stream, fgb, G2T + (size_t)i * 4 * ED * ED, g2b + (size_t)i * ED,
                 nullptr, heb, t3, nullptr, NEL, 4 * ED, ED, 0);
        ln_k<<<(NEL + 3) / 4, 256, 0, stream>>>(t3, eln2g + (size_t)i * ED, eln2b + (size_t)i * ED,
                                                el, ED, NEL, elb, lgb, local_index);

        // ---- node FFN ----
        run_gemm(stream, hb, F1T + (size_t)i * DD * 4 * DD, f1b + (size_t)i * 4 * DD,
                 nullptr, nullptr, nullptr, fgb, NN, DD, 4 * DD, 1);
        run_gemm(stream, fgb, F2T + (size_t)i * 4 * DD * DD, f2b_ + (size_t)i * DD,
                 nullptr, hb, xbuf, nullptr, NN, 2048, DD, 0);
        ln_k<<<(NN + 3) / 4, 256, 0, stream>>>(xbuf, ln2g + (size_t)i * DD, ln2b + (size_t)i * DD,
                                               xbuf, DD, NN, xb, nullptr, nullptr);
    }
    // outputs already in d_out
}

// Round 11
// 1671.866 us; speedup vs baseline: 1.3347x; 1.0804x over previous
//
#include <hip/hip_runtime.h>
#include <math.h>

#define NN   10000      // nodes
#define DD   512        // node dim
#define NH   8          // node heads (DK=64)
#define NE   120000     // edges (global)
#define NEL  60000      // local edges
#define NLG  600000     // line-graph edges
#define ED   64         // edge dim (EH=8, EDK=8)
#define NEH  8
#define NL   4          // layers
#define QKVW 1536       // fused q|k|v row width

typedef __attribute__((ext_vector_type(8))) short bf16x8;
typedef __attribute__((ext_vector_type(8))) unsigned short u16x8;
typedef __attribute__((ext_vector_type(4))) float f32x4;

__device__ __forceinline__ unsigned short f2b(float f) {
    union { float f; unsigned u; } c; c.f = f;
    unsigned u = c.u;
    unsigned r = u + 0x7FFFu + ((u >> 16) & 1u);
    return (unsigned short)(r >> 16);
}
__device__ __forceinline__ float b2f(unsigned short b) {
    union { unsigned u; float f; } c; c.u = ((unsigned)b) << 16;
    return c.f;
}

// async global->LDS, 16B per lane; LDS dest is wave-uniform base + lane*16 (HW)
__device__ __forceinline__ void gl16(const unsigned short* g, unsigned short* l) {
    __builtin_amdgcn_global_load_lds(
        (const __attribute__((address_space(1))) unsigned int*)g,
        (__attribute__((address_space(3))) unsigned int*)l, 16, 0, 0);
}

// ---------------- elementwise helpers ----------------
static __global__ __launch_bounds__(256)
void zero_k(float* __restrict__ p, int n) {
    int i = blockIdx.x * 256 + threadIdx.x;
    if (i < n) p[i] = 0.0f;
}

static __global__ __launch_bounds__(256)
void castcopy_k(const float* __restrict__ s, float* __restrict__ d,
                unsigned short* __restrict__ db, int n) {
    int i = blockIdx.x * 256 + threadIdx.x;
    if (i < n) { float v = s[i]; if (d) d[i] = v; db[i] = f2b(v); }
}

static __global__ __launch_bounds__(256)
void init_lg_k(const float* __restrict__ rel, const int* __restrict__ ef,
               unsigned short* __restrict__ lgb) {
    int i = blockIdx.x * 256 + threadIdx.x;
    if (i >= NE * ED) return;
    int e = i >> 6, c = i & 63;
    lgb[i] = f2b(rel[ef[e] * ED + c]);
}

static __global__ __launch_bounds__(256)
void gather64_k(const unsigned short* __restrict__ lgb, const int* __restrict__ idx,
                float* __restrict__ el, unsigned short* __restrict__ elb) {
    int i = blockIdx.x * 256 + threadIdx.x;
    if (i >= NEL * ED) return;
    int r = i >> 6;
    unsigned short b = lgb[(long)idx[r] * ED + (i & 63)];
    el[i] = b2f(b); elb[i] = b;
}

// ---------------- LDS-tiled transpose+cast ----------------
static __global__ __launch_bounds__(256)
void ttrans_k(const float* __restrict__ in, unsigned short* __restrict__ out,
              int K, int N, long lstride, int rowStride, int rowOff, int colOff) {
    __shared__ float sm[32][33];
    const int l = blockIdx.z;
    const int kt = blockIdx.x * 32, nt = blockIdx.y * 32;
    const int tx = threadIdx.x & 31, ty = threadIdx.x >> 5;
    const float* ip = in + (size_t)l * K * N;
    #pragma unroll
    for (int r = 0; r < 4; ++r)
        sm[ty + 8 * r][tx] = ip[(size_t)(kt + ty + 8 * r) * N + nt + tx];
    __syncthreads();
    unsigned short* op = out + (size_t)l * lstride;
    #pragma unroll
    for (int r = 0; r < 4; ++r) {
        int n = nt + ty + 8 * r;
        op[(size_t)(rowOff + n) * rowStride + colOff + kt + tx] = f2b(sm[tx][ty + 8 * r]);
    }
}

static __global__ __launch_bounds__(256)
void build_qkvb_k(const float* __restrict__ bq, float* __restrict__ out) {
    int i = blockIdx.x * 256 + threadIdx.x;
    if (i >= NL * QKVW) return;
    int l = i / QKVW, c = i - l * QKVW;
    out[i] = (c < 512) ? bq[l * 512 + c] : 0.0f;
}

static __global__ __launch_bounds__(256)
void ebias_k(const float* __restrict__ ndb, const float* __restrict__ eqb,
             const float* __restrict__ nsb, float* __restrict__ kvb,
             float* __restrict__ qb2) {
    int i = blockIdx.x * 256 + threadIdx.x;
    if (i < NL * 128) kvb[i] = ndb[(i >> 7) * 64 + (i & 63)];
    if (i < NL * 64)  qb2[i] = eqb[i] + nsb[i];
}

// ---------------- CSR build ----------------
static __global__ __launch_bounds__(256)
void hist_k(const int* __restrict__ dst, int* __restrict__ cnt, int n) {
    int i = blockIdx.x * 256 + threadIdx.x;
    if (i < n) atomicAdd(&cnt[dst[i]], 1);
}

static __global__ __launch_bounds__(256)
void scanA_k(const int* __restrict__ cnt, int* __restrict__ off,
             int* __restrict__ bsum, int n) {
    __shared__ int sm[256];
    const int t = threadIdx.x;
    const int i = blockIdx.x * 256 + t;
    int v = (i < n) ? cnt[i] : 0;
    sm[t] = v; __syncthreads();
    int x = v;
    #pragma unroll
    for (int d = 1; d < 256; d <<= 1) {
        int y = (t >= d) ? sm[t - d] : 0;
        __syncthreads();
        x += y; sm[t] = x; __syncthreads();
    }
    if (i < n) off[i] = x - v;
    if (t == 255) bsum[blockIdx.x] = x;
}

static __global__ __launch_bounds__(1024)
void scanB_k(int* __restrict__ bsum, int nb) {
    __shared__ int sm[1024];
    const int t = threadIdx.x;
    int v = (t < nb) ? bsum[t] : 0;
    sm[t] = v; __syncthreads();
    int x = v;
    #pragma unroll
    for (int d = 1; d < 1024; d <<= 1) {
        int y = (t >= d) ? sm[t - d] : 0;
        __syncthreads();
        x += y; sm[t] = x; __syncthreads();
    }
    if (t < nb) bsum[t] = x - v;
}

static __global__ __launch_bounds__(256)
void scanC_k(const int* __restrict__ bsum, int* __restrict__ off,
             int* __restrict__ cur, int n) {
    int i = blockIdx.x * 256 + threadIdx.x;
    if (i < n) { int o = off[i] + bsum[blockIdx.x]; off[i] = o; cur[i] = o; }
}

static __global__ __launch_bounds__(256)
void scatter_k(const int* __restrict__ dst, int* __restrict__ cur,
               int* __restrict__ ord, int n) {
    int i = blockIdx.x * 256 + threadIdx.x;
    if (i < n) { int p = atomicAdd(&cur[dst[i]], 1); ord[p] = i; }
}

static __global__ __launch_bounds__(256)
void pack_k(const int* __restrict__ gord, const int* __restrict__ gsrc,
            const int* __restrict__ eord, const int* __restrict__ lsrc,
            int2* __restrict__ npack, int* __restrict__ esrc) {
    int i = blockIdx.x * 256 + threadIdx.x;
    if (i < NE) { int e = gord[i]; npack[i] = make_int2(e, gsrc[e]); }
    if (i < NLG) esrc[i] = lsrc[eord[i]];
}

// ---------------- bf16 MFMA GEMM: 64x64 tile, BK=64, single-buf LDS --------
// 16KB LDS -> 8 blocks/CU (wave cap); 8 MFMA per wave per barrier pair.
// LDS row = 64 cols (128B): physical slot p holds source slot p^(r&7);
// read banks: 8 distinct 4-bank windows x 2 lanes = conflict-free (m136).
// If A2==null: C = A[M,K] @ Bt[Nc,K]^T; else A-row r = [A[r][0:K1] | A2[idx2[r]][:]]
// (requires K1 % 64 == 0). addC fp32 or addCb bf16 residual; C fp32 or Cb bf16.
static __global__ __launch_bounds__(256)
void gemm_bf16_k(const unsigned short* __restrict__ A,
                 const unsigned short* __restrict__ A2, const int* __restrict__ idx2,
                 const unsigned short* __restrict__ Bt, const float* __restrict__ bias,
                 const float* __restrict__ addC, const unsigned short* __restrict__ addCb,
                 float* __restrict__ C, unsigned short* __restrict__ Cb,
                 int M, int K, int Nc, int doRelu, int K1)
{
    __shared__ unsigned short Asl[64 * 64];
    __shared__ unsigned short Bsl[64 * 64];
    const int tid  = threadIdx.x;
    const int lane = tid & 63;
    const int wave = tid >> 6;
    const int wr = (wave >> 1) * 32;
    const int wc = (wave & 1) * 32;

    // XCD-aware bijective block swizzle (m204)
    const int nwg = gridDim.x * gridDim.y;
    const int hw = blockIdx.y * gridDim.x + blockIdx.x;
    const int q8 = nwg >> 3, r8 = nwg & 7;
    const int xcd = hw & 7, rest = hw >> 3;
    const int logical = (xcd < r8 ? xcd * (q8 + 1) : r8 * (q8 + 1) + (xcd - r8) * q8) + rest;
    const int bm = (logical / gridDim.x) * 64;
    const int bn = (logical % gridDim.x) * 64;

    // staging: one gl16 covers 8 rows x 64 cols; lane -> row lane>>3, slot lane&7
    const int rl8 = lane >> 3;                // 0..7
    const int sl8 = lane & 7;                 // 0..7
    int ga[2]; long ia[2]; bool av[2]; int acw[2];
    int gb[2]; int bcw[2];
    #pragma unroll
    for (int c = 0; c < 2; ++c) {
        int ar = wave * 16 + c * 8 + rl8;
        ga[c] = bm + ar;
        av[c] = ga[c] < M;
        ia[c] = (A2 && av[c]) ? (long)idx2[ga[c]] : 0;
        acw[c] = (sl8 ^ (ar & 7)) * 8;        // pre-swizzled source col (elems)
        int br = wave * 16 + c * 8 + rl8;
        gb[c] = bn + br;
        bcw[c] = (sl8 ^ (br & 7)) * 8;
    }

    auto stage = [&](int k0) {
        #pragma unroll
        for (int c = 0; c < 2; ++c) {
            const unsigned short* s;
            if (!A2)            s = A  + (long)ga[c] * K  + k0 + acw[c];
            else if (k0 < K1)   s = A  + (long)ga[c] * K1 + k0 + acw[c];
            else                s = A2 + ia[c] * DD + (k0 - K1) + acw[c];
            if (av[c]) gl16(s, Asl + (wave * 16 + c * 8) * 64);
            gl16(Bt + (long)gb[c] * K + k0 + bcw[c], Bsl + (wave * 16 + c * 8) * 64);
        }
    };

    f32x4 acc[2][2] = {};
    const int rbase = lane & 15;
    const int ks = lane >> 4;

    for (int k0 = 0; k0 < K; k0 += 64) {
        stage(k0);
        __syncthreads();                      // staged tile landed (vmcnt drained)
        #pragma unroll
        for (int h = 0; h < 2; ++h) {         // two K=32 halves per LDS tile
            bf16x8 af[2], bfr[2];
            #pragma unroll
            for (int mi = 0; mi < 2; ++mi) {
                int r = wr + mi * 16 + rbase;
                int p = (h * 4 + ks) ^ (r & 7);
                af[mi] = *reinterpret_cast<const bf16x8*>(Asl + r * 64 + p * 8);
            }
            #pragma unroll
            for (int ni = 0; ni < 2; ++ni) {
                int r = wc + ni * 16 + rbase;
                int p = (h * 4 + ks) ^ (r & 7);
                bfr[ni] = *reinterpret_cast<const bf16x8*>(Bsl + r * 64 + p * 8);
            }
            #pragma unroll
            for (int mi = 0; mi < 2; ++mi)
                #pragma unroll
                for (int ni = 0; ni < 2; ++ni)
                    acc[mi][ni] = __builtin_amdgcn_mfma_f32_16x16x32_bf16(
                        af[mi], bfr[ni], acc[mi][ni], 0, 0, 0);
        }
        __syncthreads();                      // ds_reads done before re-stage
    }

    const int colBase = bn + wc + rbase;
    const int rowBase = bm + wr + ks * 4;
    #pragma unroll
    for (int mi = 0; mi < 2; ++mi) {
        #pragma unroll
        for (int j = 0; j < 4; ++j) {
            int r = rowBase + mi * 16 + j;
            if (r >= M) continue;
            long ro = (long)r * Nc;
            #pragma unroll
            for (int ni = 0; ni < 2; ++ni) {
                int cc = colBase + ni * 16;
                if (cc >= Nc) continue;
                float v = acc[mi][ni][j];
                if (bias)  v += bias[cc];
                if (doRelu) v = fmaxf(v, 0.0f);
                if (addC)  v += addC[ro + cc];
                else if (addCb) v += b2f(addCb[ro + cc]);
                if (Cb) Cb[ro + cc] = f2b(v);
                else    C[ro + cc] = v;
            }
        }
    }
}

// ---------------- LayerNorm (wave per row, 4 rows/block) ----------------
// input from fp32 `in` or bf16 `inb` (exactly one non-null)
static __global__ __launch_bounds__(256)
void ln_k(const float* __restrict__ in, const unsigned short* __restrict__ inb,
          const float* __restrict__ g, const float* __restrict__ b,
          float* __restrict__ out, int Dw, int nrows,
          unsigned short* __restrict__ outb,
          unsigned short* __restrict__ out2b, const int* __restrict__ idx2)
{
    const int row = blockIdx.x * 4 + (threadIdx.x >> 6);
    if (row >= nrows) return;
    const int lane = threadIdx.x & 63;
    const int per = Dw >> 6;
    float v[8];
    float s = 0.f;
    if (inb) {
        const unsigned short* rp = inb + (long)row * Dw;
        for (int i = 0; i < per; ++i) { v[i] = b2f(rp[i * 64 + lane]); s += v[i]; }
    } else {
        const float* rp = in + (long)row * Dw;
        for (int i = 0; i < per; ++i) { v[i] = rp[i * 64 + lane]; s += v[i]; }
    }
    #pragma unroll
    for (int off = 32; off; off >>= 1) s += __shfl_xor(s, off, 64);
    const float mu = s / (float)Dw;
    float var = 0.f;
    for (int i = 0; i < per; ++i) { float d = v[i] - mu; var += d * d; }
    #pragma unroll
    for (int off = 32; off; off >>= 1) var += __shfl_xor(var, off, 64);
    const float rstd = rsqrtf(var / (float)Dw + 1e-5f);
    for (int i = 0; i < per; ++i) {
        int c = i * 64 + lane;
        float o = (v[i] - mu) * rstd * g[c] + b[c];
        if (out)   out[(long)row * Dw + c] = o;
        if (outb)  outb[(long)row * Dw + c] = f2b(o);
        if (out2b) out2b[(long)idx2[row] * Dw + c] = f2b(o);
    }
}

// ---------------- node attention, CSR, 2-way unrolled ----------------
static __global__ __launch_bounds__(256)
void node_attn_csr_k(const unsigned short* __restrict__ qkv,
                     const unsigned short* __restrict__ lgb,
                     const int* __restrict__ goff, const int2* __restrict__ npack,
                     unsigned short* __restrict__ ob)
{
    int node = blockIdx.x * 4 + (threadIdx.x >> 6);
    if (node >= NN) return;
    const int lane = threadIdx.x & 63;
    float qv[8];
    {
        u16x8 q8 = *reinterpret_cast<const u16x8*>(qkv + (long)node * QKVW + lane * 8);
        #pragma unroll
        for (int i = 0; i < 8; ++i) qv[i] = b2f(q8[i]);
    }
    float wva[8] = {0.f, 0.f, 0.f, 0.f, 0.f, 0.f, 0.f, 0.f};
    float zac = 0.f;
    int j = goff[node];
    const int hi = (node + 1 < NN) ? goff[node + 1] : NE;
    const int eoffl = (lane & 7) * 8;

    for (; j + 2 <= hi; j += 2) {
        int2 pa = npack[j], pb = npack[j + 1];
        u16x8 kA = *reinterpret_cast<const u16x8*>(qkv + (long)pa.y * QKVW + 512 + lane * 8);
        u16x8 vA = *reinterpret_cast<const u16x8*>(qkv + (long)pa.y * QKVW + 1024 + lane * 8);
        u16x8 eA = *reinterpret_cast<const u16x8*>(lgb + (long)pa.x * ED + eoffl);
        u16x8 kB = *reinterpret_cast<const u16x8*>(qkv + (long)pb.y * QKVW + 512 + lane * 8);
        u16x8 vB = *reinterpret_cast<const u16x8*>(qkv + (long)pb.y * QKVW + 1024 + lane * 8);
        u16x8 eB = *reinterpret_cast<const u16x8*>(lgb + (long)pb.x * ED + eoffl);
        float edA[8], vvA[8], edB[8], vvB[8];
        float pA = 0.f, pB = 0.f;
        #pragma unroll
        for (int i = 0; i < 8; ++i) {
            edA[i] = b2f(eA[i]); vvA[i] = b2f(vA[i]);
            pA = fmaf(b2f(kA[i]) + edA[i], qv[i], pA);
            edB[i] = b2f(eB[i]); vvB[i] = b2f(vB[i]);
            pB = fmaf(b2f(kB[i]) + edB[i], qv[i], pB);
        }
        pA += __shfl_xor(pA, 1, 64); pA += __shfl_xor(pA, 2, 64); pA += __shfl_xor(pA, 4, 64);
        pB += __shfl_xor(pB, 1, 64); pB += __shfl_xor(pB, 2, 64); pB += __shfl_xor(pB, 4, 64);
        float wA = expf(fminf(fmaxf(pA * 0.125f, -10.0f), 10.0f));
        float wB = expf(fminf(fmaxf(pB * 0.125f, -10.0f), 10.0f));
        #pragma unroll
        for (int i = 0; i < 8; ++i) {
            wva[i] = fmaf(wA, vvA[i] + edA[i], wva[i]);
            wva[i] = fmaf(wB, vvB[i] + edB[i], wva[i]);
        }
        zac += wA + wB;
    }
    for (; j < hi; ++j) {
        int2 pa = npack[j];
        u16x8 kA = *reinterpret_cast<const u16x8*>(qkv + (long)pa.y * QKVW + 512 + lane * 8);
        u16x8 vA = *reinterpret_cast<const u16x8*>(qkv + (long)pa.y * QKVW + 1024 + lane * 8);
        u16x8 eA = *reinterpret_cast<const u16x8*>(lgb + (long)pa.x * ED + eoffl);
        float edA[8], vvA[8];
        float pA = 0.f;
        #pragma unroll
        for (int i = 0; i < 8; ++i) {
            edA[i] = b2f(eA[i]); vvA[i] = b2f(vA[i]);
            pA = fmaf(b2f(kA[i]) + edA[i], qv[i], pA);
        }
        pA += __shfl_xor(pA, 1, 64); pA += __shfl_xor(pA, 2, 64); pA += __shfl_xor(pA, 4, 64);
        float wA = expf(fminf(fmaxf(pA * 0.125f, -10.0f), 10.0f));
        #pragma unroll
        for (int i = 0; i < 8; ++i) wva[i] = fmaf(wA, vvA[i] + edA[i], wva[i]);
        zac += wA;
    }
    const float inv = 1.0f / fmaxf(zac, 1e-9f);
    u16x8 o8;
    #pragma unroll
    for (int i = 0; i < 8; ++i) o8[i] = f2b(wva[i] * inv);
    *reinterpret_cast<u16x8*>(ob + (long)node * DD + lane * 8) = o8;
}

// ---------------- line-graph attention, CSR, 4-way unrolled ----------------
static __global__ __launch_bounds__(256)
void lg_attn_csr_k(const unsigned short* __restrict__ qeb,
                   const unsigned short* __restrict__ keve,
                   const int* __restrict__ eoff, const int* __restrict__ esrc,
                   unsigned short* __restrict__ oeb)
{
    int d = blockIdx.x * 4 + (threadIdx.x >> 6);
    if (d >= NEL) return;
    const int lane = threadIdx.x & 63;
    const float qv = b2f(qeb[(long)d * ED + lane]);
    float oa = 0.f, zac = 0.f;
    int j = eoff[d];
    const int hi = (d + 1 < NEL) ? eoff[d + 1] : NLG;
    for (; j + 4 <= hi; j += 4) {
        int ss[4]; float kk[4], vv[4];
        #pragma unroll
        for (int u = 0; u < 4; ++u) ss[u] = esrc[j + u];
        #pragma unroll
        for (int u = 0; u < 4; ++u) {
            kk[u] = b2f(keve[(long)ss[u] * 128 + lane]);
            vv[u] = b2f(keve[(long)ss[u] * 128 + 64 + lane]);
        }
        #pragma unroll
        for (int u = 0; u < 4; ++u) {
            float p = kk[u] * qv;
            p += __shfl_xor(p, 1, 64); p += __shfl_xor(p, 2, 64); p += __shfl_xor(p, 4, 64);
            float w = expf(fminf(fmaxf(p * 0.35355339059327373f, -10.0f), 10.0f));
            oa = fmaf(w, vv[u], oa);
            zac += w;
        }
    }
    for (; j < hi; ++j) {
        int s = esrc[j];
        float kv = b2f(keve[(long)s * 128 + lane]);
        float vv = b2f(keve[(long)s * 128 + 64 + lane]);
        float p = kv * qv;
        p += __shfl_xor(p, 1, 64); p += __shfl_xor(p, 2, 64); p += __shfl_xor(p, 4, 64);
        float w = expf(fminf(fmaxf(p * 0.35355339059327373f, -10.0f), 10.0f));
        oa = fmaf(w, vv, oa);
        zac += w;
    }
    oeb[(long)d * ED + lane] = f2b(oa / fmaxf(zac, 1e-9f));
}

// ---------------- host ----------------
static inline void run_gemm(hipStream_t st, const unsigned short* A,
                            const unsigned short* Bt, const float* bias,
                            const float* addC, const unsigned short* addCb,
                            float* C, unsigned short* Cb,
                            int M, int K, int Nc, int relu)
{
    dim3 g((Nc + 63) / 64, (M + 63) / 64);
    gemm_bf16_k<<<g, 256, 0, st>>>(A, nullptr, nullptr, Bt, bias, addC, addCb,
                                   C, Cb, M, K, Nc, relu, 0);
}
static inline void run_gemm2(hipStream_t st, const unsigned short* A1,
                             const unsigned short* A2, const int* idx2,
                             const unsigned short* Bt, const float* bias,
                             unsigned short* Cb, int M, int K, int Nc, int K1)
{
    dim3 g((Nc + 63) / 64, (M + 63) / 64);
    gemm_bf16_k<<<g, 256, 0, st>>>(A1, A2, idx2, Bt, bias, nullptr, nullptr,
                                   nullptr, Cb, M, K, Nc, 0, K1);
}

extern "C" void kernel_launch(void* const* d_in, const int* in_sizes, int n_in,
                              void* d_out, int out_size, void* d_ws, size_t ws_size,
                              hipStream_t stream)
{
    const float* x_in  = (const float*)d_in[0];
    const float* rel   = (const float*)d_in[1];
    const float* Wq    = (const float*)d_in[2];
    const float* bq    = (const float*)d_in[3];
    const float* Wk    = (const float*)d_in[4];
    const float* Wv    = (const float*)d_in[5];
    const float* Wo    = (const float*)d_in[6];
    const float* bo    = (const float*)d_in[7];
    const float* ln1g  = (const float*)d_in[8];
    const float* ln1b  = (const float*)d_in[9];
    const float* F1    = (const float*)d_in[10];
    const float* f1b   = (const float*)d_in[11];
    const float* F2    = (const float*)d_in[12];
    const float* f2b_  = (const float*)d_in[13];
    const float* ln2g  = (const float*)d_in[14];
    const float* ln2b  = (const float*)d_in[15];
    const float* Eq    = (const float*)d_in[16];
    const float* eqb   = (const float*)d_in[17];
    const float* Ek    = (const float*)d_in[18];
    const float* Ev    = (const float*)d_in[19];
    const float* Eo    = (const float*)d_in[20];
    const float* eob   = (const float*)d_in[21];
    const float* Ns    = (const float*)d_in[22];
    const float* nsb   = (const float*)d_in[23];
    const float* Nd    = (const float*)d_in[24];
    const float* ndb   = (const float*)d_in[25];
    const float* eln1g = (const float*)d_in[26];
    const float* eln1b = (const float*)d_in[27];
    const float* G1    = (const float*)d_in[28];
    const float* g1b   = (const float*)d_in[29];
    const float* G2    = (const float*)d_in[30];
    const float* g2b   = (const float*)d_in[31];
    const float* eln2g = (const float*)d_in[32];
    const float* eln2b = (const float*)d_in[33];
    const int* edge_feat   = (const int*)d_in[34];
    const int* local_index = (const int*)d_in[35];
    const int* src_ids     = (const int*)d_in[36];
    const int* dst_ids     = (const int*)d_in[37];
    const int* g_src       = (const int*)d_in[38];
    const int* g_dst       = (const int*)d_in[39];
    const int* lg_src      = (const int*)d_in[40];
    const int* lg_dst      = (const int*)d_in[41];

    // outputs live in d_out
    float* xbuf = (float*)d_out;                   // (NN, DD)
    float* el   = xbuf + (size_t)NN * DD;          // (NEL, ED)

    // ---- workspace layout ----
    float* W = (float*)d_ws;
    size_t off = 0;
    auto alloc = [&](size_t n) { float* p = W + off; off += (n + 63) & ~(size_t)63; return p; };
    float* qkvb = alloc((size_t)NL * QKVW);
    float* kvb  = alloc((size_t)NL * 128);
    float* qb2  = alloc((size_t)NL * ED);

    unsigned short* bp = (unsigned short*)(W + off);
    size_t boff = 0;
    auto balloc = [&](size_t n) { unsigned short* p = bp + boff; boff += (n + 63) & ~(size_t)63; return p; };
    unsigned short* lgb = balloc((size_t)NE * ED);
    unsigned short* xb  = balloc((size_t)NN * DD);
    unsigned short* qkv = balloc((size_t)NN * QKVW);
    unsigned short* elb = balloc((size_t)NEL * ED);
    unsigned short* e1b = balloc((size_t)NEL * ED);
    unsigned short* heb = balloc((size_t)NEL * ED);
    unsigned short* qeb = balloc((size_t)NEL * ED);
    unsigned short* fgb = balloc((size_t)NN * 4 * DD);
    unsigned short* t0b = balloc((size_t)NN * DD);    // pre-LN h
    unsigned short* t2b = balloc((size_t)NEL * ED);   // pre-LN he
    unsigned short* t3b = balloc((size_t)NEL * ED);   // pre-LN edge out
    unsigned short* xpb = balloc((size_t)NN * DD);    // pre-LN x
    unsigned short* hb   = qkv;
    unsigned short* keve = qkv + (size_t)NN * DD;
    unsigned short* ob   = fgb;
    unsigned short* WqkvT = balloc((size_t)NL * QKVW * DD);
    unsigned short* WoT  = balloc((size_t)NL * DD * DD);
    unsigned short* F1T  = balloc((size_t)NL * DD * 4 * DD);
    unsigned short* F2T  = balloc((size_t)NL * 4 * DD * DD);
    unsigned short* KVET = balloc((size_t)NL * 128 * 576);
    unsigned short* QET  = balloc((size_t)NL * 64 * 576);
    unsigned short* EoT  = balloc((size_t)NL * ED * ED);
    unsigned short* G1T  = balloc((size_t)NL * ED * 4 * ED);
    unsigned short* G2T  = balloc((size_t)NL * 4 * ED * ED);
    int* ip = (int*)(bp + ((boff + 63) & ~(size_t)63));
    size_t ioff = 0;
    auto ialloc = [&](size_t n) { int* p = ip + ioff; ioff += (n + 63) & ~(size_t)63; return p; };
    int* gcnt = ialloc(NN);
    int* goff = ialloc(NN);
    int* gcur = ialloc(NN);
    int* gord = ialloc(NE);
    int2* npack = (int2*)ialloc(2 * (size_t)NE);
    int* ecnt = ialloc(NEL);
    int* eoff = ialloc(NEL);
    int* ecur = ialloc(NEL);
    int* eord = ialloc(NLG);
    int* esrc = ialloc(NLG);
    int* bsum = ialloc(1024);

    // ---- weight prep ----
    auto tt = [&](const float* src, unsigned short* dst, int K, int N,
                  long lstride, int rowStride, int rowOff, int colOff) {
        dim3 g(K / 32, N / 32, NL);
        ttrans_k<<<g, 256, 0, stream>>>(src, dst, K, N, lstride, rowStride, rowOff, colOff);
    };
    tt(Wq, WqkvT, 512, 512, (long)QKVW * DD, DD, 0, 0);
    tt(Wk, WqkvT, 512, 512, (long)QKVW * DD, DD, 512, 0);
    tt(Wv, WqkvT, 512, 512, (long)QKVW * DD, DD, 1024, 0);
    tt(Wo, WoT, 512, 512, (long)DD * DD, DD, 0, 0);
    tt(F1, F1T, 512, 2048, (long)DD * 4 * DD, DD, 0, 0);
    tt(F2, F2T, 2048, 512, (long)4 * DD * DD, 4 * DD, 0, 0);
    tt(Ek, KVET, 64, 64, (long)128 * 576, 576, 0, 0);
    tt(Nd, KVET, 512, 64, (long)128 * 576, 576, 0, 64);
    tt(Ev, KVET, 64, 64, (long)128 * 576, 576, 64, 0);
    tt(Nd, KVET, 512, 64, (long)128 * 576, 576, 64, 64);
    tt(Eq, QET, 64, 64, (long)64 * 576, 576, 0, 0);
    tt(Ns, QET, 512, 64, (long)64 * 576, 576, 0, 64);
    tt(Eo, EoT, 64, 64, (long)ED * ED, ED, 0, 0);
    tt(G1, G1T, 64, 256, (long)ED * 4 * ED, ED, 0, 0);
    tt(G2, G2T, 256, 64, (long)4 * ED * ED, 4 * ED, 0, 0);
    build_qkvb_k<<<(NL * QKVW + 255) / 256, 256, 0, stream>>>(bq, qkvb);
    ebias_k<<<(NL * 128 + 255) / 256, 256, 0, stream>>>(ndb, eqb, nsb, kvb, qb2);

    // ---- CSR build ----
    const int nbG = (NN + 255) / 256, nbE = (NEL + 255) / 256;
    zero_k<<<nbG, 256, 0, stream>>>((float*)gcnt, NN);
    hist_k<<<(NE + 255) / 256, 256, 0, stream>>>(g_dst, gcnt, NE);
    scanA_k<<<nbG, 256, 0, stream>>>(gcnt, goff, bsum, NN);
    scanB_k<<<1, 1024, 0, stream>>>(bsum, nbG);
    scanC_k<<<nbG, 256, 0, stream>>>(bsum, goff, gcur, NN);
    scatter_k<<<(NE + 255) / 256, 256, 0, stream>>>(g_dst, gcur, gord, NE);
    zero_k<<<nbE, 256, 0, stream>>>((float*)ecnt, NEL);
    hist_k<<<(NLG + 255) / 256, 256, 0, stream>>>(lg_dst, ecnt, NLG);
    scanA_k<<<nbE, 256, 0, stream>>>(ecnt, eoff, bsum, NEL);
    scanB_k<<<1, 1024, 0, stream>>>(bsum, nbE);
    scanC_k<<<nbE, 256, 0, stream>>>(bsum, eoff, ecur, NEL);
    scatter_k<<<(NLG + 255) / 256, 256, 0, stream>>>(lg_dst, ecur, eord, NLG);
    pack_k<<<(NLG + 255) / 256, 256, 0, stream>>>(gord, g_src, eord, lg_src, npack, esrc);

    const int ndD = NN * DD;
    const int elD = NEL * ED;
    castcopy_k<<<(ndD + 255) / 256, 256, 0, stream>>>(x_in, xbuf, xb, ndD);
    init_lg_k<<<(NE * ED + 255) / 256, 256, 0, stream>>>(rel, edge_feat, lgb);
    gather64_k<<<(elD + 255) / 256, 256, 0, stream>>>(lgb, local_index, el, elb);

    for (int i = 0; i < NL; ++i) {
        size_t oD2 = (size_t)i * DD * DD, oE2 = (size_t)i * ED * ED;

        // ---- node attention (reads lgb BEFORE this layer's edge update) ----
        run_gemm(stream, xb, WqkvT + (size_t)i * QKVW * DD, qkvb + (size_t)i * QKVW,
                 nullptr, nullptr, nullptr, qkv, NN, DD, QKVW, 0);
        node_attn_csr_k<<<NN / 4, 256, 0, stream>>>(qkv, lgb, goff, npack, ob);
        // t0b = bf16(x_in + o @ Wo + bo)
        run_gemm(stream, ob, WoT + oD2, bo + (size_t)i * DD, nullptr, xb, nullptr, t0b, NN, DD, DD, 0);
        ln_k<<<(NN + 3) / 4, 256, 0, stream>>>(nullptr, t0b, ln1g + (size_t)i * DD, ln1b + (size_t)i * DD,
                                               nullptr, DD, NN, hb, nullptr, nullptr);

        // ---- edge branch (fused split-K GEMMs) ----
        run_gemm2(stream, elb, xb, dst_ids, KVET + (size_t)i * 128 * 576,
                  kvb + (size_t)i * 128, keve, NEL, 576, 128, 64);
        run_gemm2(stream, elb, xb, src_ids, QET + (size_t)i * 64 * 576,
                  qb2 + (size_t)i * 64, qeb, NEL, 576, 64, 64);
        lg_attn_csr_k<<<NEL / 4, 256, 0, stream>>>(qeb, keve, eoff, esrc, e1b);
        // t2b = bf16(el + oe @ Eo + eob)
        run_gemm(stream, e1b, EoT + oE2, eob + (size_t)i * ED, nullptr, elb, nullptr, t2b, NEL, ED, ED, 0);
        ln_k<<<(NEL + 3) / 4, 256, 0, stream>>>(nullptr, t2b, eln1g + (size_t)i * ED, eln1b + (size_t)i * ED,
                                                nullptr, ED, NEL, heb, nullptr, nullptr);
        run_gemm(stream, heb, G1T + (size_t)i * ED * 4 * ED, g1b + (size_t)i * 4 * ED,
                 nullptr, nullptr, nullptr, fgb, NEL, ED, 4 * ED, 1);
        run_gemm(stream, fgb, G2T + (size_t)i * 4 * ED * ED, g2b + (size_t)i * ED,
                 nullptr, heb, nullptr, t3b, NEL, 4 * ED, ED, 0);
        ln_k<<<(NEL + 3) / 4, 256, 0, stream>>>(nullptr, t3b, eln2g + (size_t)i * ED, eln2b + (size_t)i * ED,
                                                el, ED, NEL, elb, lgb, local_index);

        // ---- node FFN ----
        run_gemm(stream, hb, F1T + (size_t)i * DD * 4 * DD, f1b + (size_t)i * 4 * DD,
                 nullptr, nullptr, nullptr, fgb, NN, DD, 4 * DD, 1);
        run_gemm(stream, fgb, F2T + (size_t)i * 4 * DD * DD, f2b_ + (size_t)i * DD,
                 nullptr, hb, nullptr, xpb, NN, 2048, DD, 0);
        ln_k<<<(NN + 3) / 4, 256, 0, stream>>>(nullptr, xpb, ln2g + (size_t)i * DD, ln2b + (size_t)i * DD,
                                               xbuf, DD, NN, xb, nullptr, nullptr);
    }
    // outputs already in d_out
}